// Round 1
// baseline (784.017 us; speedup 1.0000x reference)
//
#include <hip/hip_runtime.h>
#include <stdint.h>

#define N_TOK 8192
#define DDIM  1024
#define NEXP  16
#define HDIM  1024
#define SHDIM 2048
#define TM 128
#define TN 64
#define BK 64
#define SA 72          // LDS row stride in bf16 elems (144B, 16B-aligned, breaks bank conflicts)
#define MT_R 144       // max routed m-tiles: 16384 + 16*127 padded -> <= 18432 rows

typedef __bf16 bf16x8 __attribute__((ext_vector_type(8)));
typedef float  f32x4  __attribute__((ext_vector_type(4)));
typedef short  s16x8  __attribute__((ext_vector_type(8)));

__device__ __forceinline__ unsigned short f2bf(float f) {
  union { float f; unsigned u; } v; v.f = f;
  unsigned r = v.u + 0x7fffu + ((v.u >> 16) & 1u);
  return (unsigned short)(r >> 16);
}

// ---------------- small setup kernels ----------------

__global__ void k_zero(int* cnt, int* cursor) {
  if (threadIdx.x < NEXP) { cnt[threadIdx.x] = 0; cursor[threadIdx.x] = 0; }
}

__global__ __launch_bounds__(256) void k_router(
    const float* __restrict__ x, const float* __restrict__ rw,
    const float* __restrict__ rb, int* __restrict__ cnt,
    int* __restrict__ tok_idx, float* __restrict__ tok_w,
    float* __restrict__ probs) {
  const int lane = threadIdx.x & 63;
  const int tok  = blockIdx.x * 4 + (threadIdx.x >> 6);
  const float* xr = x + (size_t)tok * DDIM;
  float acc[NEXP];
#pragma unroll
  for (int e = 0; e < NEXP; e++) acc[e] = 0.f;
  for (int d = lane; d < DDIM; d += 64) {
    float xv = xr[d];
    const float* wp = rw + d * NEXP;
#pragma unroll
    for (int e = 0; e < NEXP; e++) acc[e] = fmaf(xv, wp[e], acc[e]);
  }
#pragma unroll
  for (int e = 0; e < NEXP; e++) {
    float v = acc[e];
#pragma unroll
    for (int o = 32; o; o >>= 1) v += __shfl_xor(v, o);
    acc[e] = v;
  }
  if (lane != 0) return;
  float mx = acc[0];
#pragma unroll
  for (int e = 1; e < NEXP; e++) mx = fmaxf(mx, acc[e]);
  float p[NEXP]; float s = 0.f;
#pragma unroll
  for (int e = 0; e < NEXP; e++) { p[e] = __expf(acc[e] - mx); s += p[e]; }
  float inv = 1.f / s;
  float* pdst = probs + (size_t)tok * NEXP;
#pragma unroll
  for (int e = 0; e < NEXP; e++) { p[e] *= inv; pdst[e] = p[e]; }
  // top-2 on logits + bias, ties -> lower index (strict > keeps first)
  int i0 = 0; float b0 = acc[0] + rb[0];
#pragma unroll
  for (int e = 1; e < NEXP; e++) { float v = acc[e] + rb[e]; if (v > b0) { b0 = v; i0 = e; } }
  int i1 = -1; float b1 = -3.4e38f;
#pragma unroll
  for (int e = 0; e < NEXP; e++) {
    if (e == i0) continue;
    float v = acc[e] + rb[e]; if (v > b1) { b1 = v; i1 = e; }
  }
  float w0 = 0.f, w1 = 0.f;
#pragma unroll
  for (int e = 0; e < NEXP; e++) { if (e == i0) w0 = p[e]; if (e == i1) w1 = p[e]; }
  float ssum = fmaxf(w0 + w1, 1e-9f);
  w0 /= ssum; w1 /= ssum;
  atomicAdd(&cnt[i0], 1); atomicAdd(&cnt[i1], 1);
  tok_idx[tok * 2]     = i0; tok_idx[tok * 2 + 1] = i1;
  tok_w[tok * 2]       = w0; tok_w[tok * 2 + 1]   = w1;
}

__global__ void k_prefix(const int* __restrict__ cnt, int* __restrict__ offs) {
  if (threadIdx.x == 0) {
    int o = 0;
    for (int e = 0; e < NEXP; e++) { offs[e] = o; o += ((cnt[e] + 127) & ~127); }
    offs[NEXP] = o;
  }
}

__global__ void k_f32_to_bf16(const float* __restrict__ src,
                              unsigned short* __restrict__ dst, int n4) {
  int i = blockIdx.x * blockDim.x + threadIdx.x;
  if (i >= n4) return;
  float4 v = ((const float4*)src)[i];
  ushort4 o;
  o.x = f2bf(v.x); o.y = f2bf(v.y); o.z = f2bf(v.z); o.w = f2bf(v.w);
  ((ushort4*)dst)[i] = o;
}

// src [R][C] fp32 -> dst [C][R] bf16, per-matrix offset via blockIdx.z
__global__ __launch_bounds__(256) void k_transpose(
    const float* __restrict__ src, unsigned short* __restrict__ dst, int R, int C) {
  __shared__ float tile[32][33];
  size_t mat = (size_t)blockIdx.z * R * C;
  src += mat; dst += mat;
  int tc = blockIdx.x * 32, tr = blockIdx.y * 32;
  int lx = threadIdx.x & 31, ly = threadIdx.x >> 5;
#pragma unroll
  for (int i = 0; i < 32; i += 8)
    tile[ly + i][lx] = src[(size_t)(tr + ly + i) * C + tc + lx];
  __syncthreads();
#pragma unroll
  for (int i = 0; i < 32; i += 8)
    dst[(size_t)(tc + ly + i) * R + tr + lx] = f2bf(tile[lx][ly + i]);
}

__global__ __launch_bounds__(256) void k_gather(
    const unsigned short* __restrict__ Xbf, const int* __restrict__ tok_idx,
    const float* __restrict__ tok_w, int* __restrict__ cursor,
    const int* __restrict__ offs, unsigned short* __restrict__ Xg,
    int* __restrict__ row_token, float* __restrict__ row_w) {
  int tok = blockIdx.x;
  __shared__ int rows[2];
  if (threadIdx.x < 2) {
    int e   = tok_idx[tok * 2 + threadIdx.x];
    int pos = atomicAdd(&cursor[e], 1);
    int row = offs[e] + pos;
    rows[threadIdx.x] = row;
    row_token[row] = tok;
    row_w[row]     = tok_w[tok * 2 + threadIdx.x];
  }
  __syncthreads();
  int slot = threadIdx.x >> 7;    // 0/1
  int c    = threadIdx.x & 127;   // 128 x 16B = 2048B = 1024 bf16
  int row  = rows[slot];
  const uint4* s = (const uint4*)(Xbf + (size_t)tok * DDIM);
  uint4* d = (uint4*)(Xg + (size_t)row * DDIM);
  d[c] = s[c];
}

// ---------------- GEMM kernels ----------------
// Tile 128x64, BK=64, 4 waves (2x2), per-wave 64x32 = 4x2 frags of 16x16x32.
// A,B both row-major-[row][k] bf16 -> ds_read_b128 fragments, consistent k-map.

template <bool ROUTED>
__global__ __launch_bounds__(256, 2) void k_gateup(
    const unsigned short* __restrict__ Abase,   // [Mrows][1024]
    const unsigned short* __restrict__ BgAll,   // [?][1024] (xpose), per-expert 1M elems
    const unsigned short* __restrict__ BuAll,
    unsigned short* __restrict__ Hout,          // [Mrows][Nh]
    int Nh,
    const int* __restrict__ offs, const int* __restrict__ cnt) {
  __shared__ unsigned short As[TM * SA];
  __shared__ unsigned short Bgs[TN * SA];
  __shared__ unsigned short Bus[TN * SA];

  const int tm = blockIdx.x * TM;
  const int tn = blockIdx.y * TN;

  int validEnd = 0x7fffffff;
  const unsigned short* Bg = BgAll;
  const unsigned short* Bu = BuAll;
  if constexpr (ROUTED) {
    if (tm >= offs[NEXP]) return;
    int e = 0;
#pragma unroll
    for (int i = 1; i < NEXP; i++) if (tm >= offs[i]) e = i;
    validEnd = offs[e] + cnt[e];
    Bg = BgAll + (size_t)e * HDIM * DDIM;
    Bu = BuAll + (size_t)e * HDIM * DDIM;
  }

  const int t = threadIdx.x;
  const unsigned short* Arow = Abase + (size_t)tm * DDIM;

  s16x8 ra[4], rg[2], ru[2];
  auto stage_load = [&](int k0) {
#pragma unroll
    for (int j = 0; j < 4; j++) {
      int c = t + 256 * j; int r = c >> 3, cx = c & 7;
      ra[j] = *(const s16x8*)(Arow + (size_t)r * DDIM + k0 + cx * 8);
    }
#pragma unroll
    for (int j = 0; j < 2; j++) {
      int c = t + 256 * j; int r = c >> 3, cx = c & 7;
      rg[j] = *(const s16x8*)(Bg + (size_t)(tn + r) * DDIM + k0 + cx * 8);
      ru[j] = *(const s16x8*)(Bu + (size_t)(tn + r) * DDIM + k0 + cx * 8);
    }
  };
  auto stage_write = [&]() {
#pragma unroll
    for (int j = 0; j < 4; j++) {
      int c = t + 256 * j; int r = c >> 3, cx = c & 7;
      *(s16x8*)(&As[r * SA + cx * 8]) = ra[j];
    }
#pragma unroll
    for (int j = 0; j < 2; j++) {
      int c = t + 256 * j; int r = c >> 3, cx = c & 7;
      *(s16x8*)(&Bgs[r * SA + cx * 8]) = rg[j];
      *(s16x8*)(&Bus[r * SA + cx * 8]) = ru[j];
    }
  };

  f32x4 accG[4][2] = {};
  f32x4 accU[4][2] = {};

  const int lane = t & 63;
  const int wv = t >> 6, wr = wv >> 1, wc = wv & 1;
  const int rbase = lane & 15;
  const int kq = (lane >> 4) * 8;

  stage_load(0);
  for (int k0 = 0; k0 < DDIM; k0 += BK) {
    if (k0) __syncthreads();
    stage_write();
    __syncthreads();
    if (k0 + BK < DDIM) stage_load(k0 + BK);
#pragma unroll
    for (int kk = 0; kk < 2; kk++) {
      bf16x8 af[4], gf[2], uf[2];
#pragma unroll
      for (int i = 0; i < 4; i++)
        af[i] = *(const bf16x8*)(&As[(wr * 64 + i * 16 + rbase) * SA + kk * 32 + kq]);
#pragma unroll
      for (int j = 0; j < 2; j++) {
        gf[j] = *(const bf16x8*)(&Bgs[(wc * 32 + j * 16 + rbase) * SA + kk * 32 + kq]);
        uf[j] = *(const bf16x8*)(&Bus[(wc * 32 + j * 16 + rbase) * SA + kk * 32 + kq]);
      }
#pragma unroll
      for (int i = 0; i < 4; i++)
#pragma unroll
        for (int j = 0; j < 2; j++) {
          accG[i][j] = __builtin_amdgcn_mfma_f32_16x16x32_bf16(af[i], gf[j], accG[i][j], 0, 0, 0);
          accU[i][j] = __builtin_amdgcn_mfma_f32_16x16x32_bf16(af[i], uf[j], accU[i][j], 0, 0, 0);
        }
    }
  }

  const int orow0 = tm + wr * 64 + (lane >> 4) * 4;
  const int ocol0 = tn + wc * 32 + (lane & 15);
#pragma unroll
  for (int i = 0; i < 4; i++)
#pragma unroll
    for (int j = 0; j < 2; j++)
#pragma unroll
      for (int r = 0; r < 4; r++) {
        int row = orow0 + i * 16 + r;
        if (row < validEnd) {
          float g = accG[i][j][r], u = accU[i][j][r];
          float h = g / (1.f + __expf(-g)) * u;   // silu(g)*u
          Hout[(size_t)row * Nh + ocol0 + j * 16] = f2bf(h);
        }
      }
}

template <bool ROUTED>
__global__ __launch_bounds__(256, 2) void k_down(
    const unsigned short* __restrict__ Abase,  // [Mrows][K]
    const unsigned short* __restrict__ BAll,   // [1024][K] (xpose), per-expert DDIM*K
    float* __restrict__ out,                   // [8192][1024]
    int K,
    const int* __restrict__ offs, const int* __restrict__ cnt,
    const int* __restrict__ row_token, const float* __restrict__ row_w) {
  __shared__ unsigned short As[TM * SA];
  __shared__ unsigned short Bs[TN * SA];

  const int tm = blockIdx.x * TM;
  const int tn = blockIdx.y * TN;

  int validEnd = 0x7fffffff;
  const unsigned short* B = BAll;
  if constexpr (ROUTED) {
    if (tm >= offs[NEXP]) return;
    int e = 0;
#pragma unroll
    for (int i = 1; i < NEXP; i++) if (tm >= offs[i]) e = i;
    validEnd = offs[e] + cnt[e];
    B = BAll + (size_t)e * DDIM * K;
  }

  const int t = threadIdx.x;
  const unsigned short* Arow = Abase + (size_t)tm * K;

  s16x8 ra[4], rb2[2];
  auto stage_load = [&](int k0) {
#pragma unroll
    for (int j = 0; j < 4; j++) {
      int c = t + 256 * j; int r = c >> 3, cx = c & 7;
      ra[j] = *(const s16x8*)(Arow + (size_t)r * K + k0 + cx * 8);
    }
#pragma unroll
    for (int j = 0; j < 2; j++) {
      int c = t + 256 * j; int r = c >> 3, cx = c & 7;
      rb2[j] = *(const s16x8*)(B + (size_t)(tn + r) * K + k0 + cx * 8);
    }
  };
  auto stage_write = [&]() {
#pragma unroll
    for (int j = 0; j < 4; j++) {
      int c = t + 256 * j; int r = c >> 3, cx = c & 7;
      *(s16x8*)(&As[r * SA + cx * 8]) = ra[j];
    }
#pragma unroll
    for (int j = 0; j < 2; j++) {
      int c = t + 256 * j; int r = c >> 3, cx = c & 7;
      *(s16x8*)(&Bs[r * SA + cx * 8]) = rb2[j];
    }
  };

  f32x4 acc[4][2] = {};

  const int lane = t & 63;
  const int wv = t >> 6, wr = wv >> 1, wc = wv & 1;
  const int rbase = lane & 15;
  const int kq = (lane >> 4) * 8;

  stage_load(0);
  for (int k0 = 0; k0 < K; k0 += BK) {
    if (k0) __syncthreads();
    stage_write();
    __syncthreads();
    if (k0 + BK < K) stage_load(k0 + BK);
#pragma unroll
    for (int kk = 0; kk < 2; kk++) {
      bf16x8 af[4], bf[2];
#pragma unroll
      for (int i = 0; i < 4; i++)
        af[i] = *(const bf16x8*)(&As[(wr * 64 + i * 16 + rbase) * SA + kk * 32 + kq]);
#pragma unroll
      for (int j = 0; j < 2; j++)
        bf[j] = *(const bf16x8*)(&Bs[(wc * 32 + j * 16 + rbase) * SA + kk * 32 + kq]);
#pragma unroll
      for (int i = 0; i < 4; i++)
#pragma unroll
        for (int j = 0; j < 2; j++)
          acc[i][j] = __builtin_amdgcn_mfma_f32_16x16x32_bf16(af[i], bf[j], acc[i][j], 0, 0, 0);
    }
  }

  const int orow0 = tm + wr * 64 + (lane >> 4) * 4;
  const int ocol0 = tn + wc * 32 + (lane & 15);
#pragma unroll
  for (int i = 0; i < 4; i++)
#pragma unroll
    for (int j = 0; j < 2; j++)
#pragma unroll
      for (int r = 0; r < 4; r++) {
        int row = orow0 + i * 16 + r;
        int col = ocol0 + j * 16;
        if constexpr (ROUTED) {
          if (row < validEnd) {
            int tok = row_token[row];
            float w = row_w[row];
            atomicAdd(&out[(size_t)tok * DDIM + col], acc[i][j][r] * w);
          }
        } else {
          out[(size_t)row * DDIM + col] = acc[i][j][r];
        }
      }
}

__global__ __launch_bounds__(256) void k_finalize(
    const float* __restrict__ probs, const int* __restrict__ cnt,
    float* __restrict__ out_tail) {
  float s[NEXP];
#pragma unroll
  for (int e = 0; e < NEXP; e++) s[e] = 0.f;
  for (int tok = threadIdx.x; tok < N_TOK; tok += 256) {
    const float* p = probs + (size_t)tok * NEXP;
#pragma unroll
    for (int e = 0; e < NEXP; e++) s[e] += p[e];
  }
  __shared__ float red[4][NEXP];
  int lane = threadIdx.x & 63, wv = threadIdx.x >> 6;
#pragma unroll
  for (int e = 0; e < NEXP; e++) {
    float v = s[e];
#pragma unroll
    for (int o = 32; o; o >>= 1) v += __shfl_xor(v, o);
    s[e] = v;
  }
  if (lane == 0) {
#pragma unroll
    for (int e = 0; e < NEXP; e++) red[wv][e] = s[e];
  }
  __syncthreads();
  if (threadIdx.x == 0) {
    float bal = 0.f;
    for (int e = 0; e < NEXP; e++) {
      float psum = red[0][e] + red[1][e] + red[2][e] + red[3][e];
      float frac = (float)cnt[e] / (float)(N_TOK * 2);
      bal += frac * (psum / (float)N_TOK);
    }
    out_tail[0] = 0.01f * (float)NEXP * bal;
  }
  if (threadIdx.x < NEXP) out_tail[1 + threadIdx.x] = (float)cnt[threadIdx.x];
}

// ---------------- launch ----------------

extern "C" void kernel_launch(void* const* d_in, const int* in_sizes, int n_in,
                              void* d_out, int out_size, void* d_ws, size_t ws_size,
                              hipStream_t stream) {
  const float* x   = (const float*)d_in[0];
  const float* rw  = (const float*)d_in[1];
  const float* rb  = (const float*)d_in[2];
  const float* Wg  = (const float*)d_in[3];
  const float* Wu  = (const float*)d_in[4];
  const float* Wd  = (const float*)d_in[5];
  const float* sWg = (const float*)d_in[6];
  const float* sWu = (const float*)d_in[7];
  const float* sWd = (const float*)d_in[8];
  float* out = (float*)d_out;

  uint8_t* w = (uint8_t*)d_ws;
  size_t off = 0;
  auto alloc = [&](size_t bytes) -> void* {
    void* p = w + off;
    off += (bytes + 255) & ~(size_t)255;
    return p;
  };

  int*   cnt     = (int*)alloc(NEXP * 4);
  int*   cursor  = (int*)alloc(NEXP * 4);
  int*   offs    = (int*)alloc((NEXP + 1) * 4);
  int*   tok_idx = (int*)alloc((size_t)N_TOK * 2 * 4);
  float* tok_w   = (float*)alloc((size_t)N_TOK * 2 * 4);
  int*   row_tok = (int*)alloc((size_t)MT_R * TM * 4);
  float* row_w   = (float*)alloc((size_t)MT_R * TM * 4);
  float* probs   = (float*)alloc((size_t)N_TOK * NEXP * 4);
  unsigned short* Xbf  = (unsigned short*)alloc((size_t)N_TOK * DDIM * 2);
  unsigned short* Xg   = (unsigned short*)alloc((size_t)MT_R * TM * DDIM * 2);
  unsigned short* Hbuf = (unsigned short*)alloc((size_t)MT_R * TM * DDIM * 2); // also holds 8192x2048 shared H
  unsigned short* WgT  = (unsigned short*)alloc((size_t)NEXP * HDIM * DDIM * 2);
  unsigned short* WuT  = (unsigned short*)alloc((size_t)NEXP * HDIM * DDIM * 2);
  unsigned short* WdT  = (unsigned short*)alloc((size_t)NEXP * DDIM * HDIM * 2);
  unsigned short* sWgT = (unsigned short*)alloc((size_t)SHDIM * DDIM * 2);
  unsigned short* sWuT = (unsigned short*)alloc((size_t)SHDIM * DDIM * 2);
  unsigned short* sWdT = (unsigned short*)alloc((size_t)DDIM * SHDIM * 2);

  if (off > ws_size) return;  // workspace insufficient -> fail cleanly

  k_zero<<<1, 64, 0, stream>>>(cnt, cursor);
  k_router<<<N_TOK / 4, 256, 0, stream>>>(x, rw, rb, cnt, tok_idx, tok_w, probs);
  k_prefix<<<1, 1, 0, stream>>>(cnt, offs);
  k_f32_to_bf16<<<(N_TOK * DDIM / 4 + 255) / 256, 256, 0, stream>>>(x, Xbf, N_TOK * DDIM / 4);

  // weight transposes (fp32 [R][C] -> bf16 [C][R])
  k_transpose<<<dim3(HDIM / 32, DDIM / 32, NEXP), 256, 0, stream>>>(Wg, WgT, DDIM, HDIM);
  k_transpose<<<dim3(HDIM / 32, DDIM / 32, NEXP), 256, 0, stream>>>(Wu, WuT, DDIM, HDIM);
  k_transpose<<<dim3(DDIM / 32, HDIM / 32, NEXP), 256, 0, stream>>>(Wd, WdT, HDIM, DDIM);
  k_transpose<<<dim3(SHDIM / 32, DDIM / 32, 1), 256, 0, stream>>>(sWg, sWgT, DDIM, SHDIM);
  k_transpose<<<dim3(SHDIM / 32, DDIM / 32, 1), 256, 0, stream>>>(sWu, sWuT, DDIM, SHDIM);
  k_transpose<<<dim3(DDIM / 32, SHDIM / 32, 1), 256, 0, stream>>>(sWd, sWdT, SHDIM, DDIM);

  k_gather<<<N_TOK, 256, 0, stream>>>(Xbf, tok_idx, tok_w, cursor, offs, Xg, row_tok, row_w);

  // shared expert: H = silu(X sWg) * (X sWu); out = H sWd (plain store, resets out)
  k_gateup<false><<<dim3(N_TOK / TM, SHDIM / TN), 256, 0, stream>>>(
      Xbf, sWgT, sWuT, Hbuf, SHDIM, nullptr, nullptr);
  k_down<false><<<dim3(N_TOK / TM, DDIM / TN), 256, 0, stream>>>(
      Hbuf, sWdT, out, SHDIM, nullptr, nullptr, nullptr, nullptr);

  // routed experts (atomic add on top of shared)
  k_gateup<true><<<dim3(MT_R, HDIM / TN), 256, 0, stream>>>(
      Xg, WgT, WuT, Hbuf, HDIM, offs, cnt);
  k_down<true><<<dim3(MT_R, DDIM / TN), 256, 0, stream>>>(
      Hbuf, WdT, out, HDIM, offs, cnt, row_tok, row_w);

  k_finalize<<<1, 256, 0, stream>>>(probs, cnt, out + (size_t)N_TOK * DDIM);
}

// Round 2
// 640.563 us; speedup vs baseline: 1.2239x; 1.2239x over previous
//
#include <hip/hip_runtime.h>
#include <stdint.h>

#define N_TOK 8192
#define DDIM  1024
#define NEXP  16
#define HDIM  1024
#define SHDIM 2048
#define TM 128
#define BK 64
#define MT_R 144       // max routed m-tiles: 16384 + 15*127 padded -> <= 18432 rows

typedef __bf16 bf16x8 __attribute__((ext_vector_type(8)));
typedef float  f32x4  __attribute__((ext_vector_type(4)));

__device__ __forceinline__ unsigned short f2bf(float f) {
  union { float f; unsigned u; } v; v.f = f;
  unsigned r = v.u + 0x7fffu + ((v.u >> 16) & 1u);
  return (unsigned short)(r >> 16);
}

__device__ __forceinline__ void gload16(const void* g, void* l) {
  __builtin_amdgcn_global_load_lds(
      (const __attribute__((address_space(1))) void*)g,
      (__attribute__((address_space(3))) void*)l, 16, 0, 0);
}

// ---------------- small setup kernels ----------------

__global__ void k_zero(int* cnt, int* cursor, float* probsum) {
  if (threadIdx.x < NEXP) {
    cnt[threadIdx.x] = 0; cursor[threadIdx.x] = 0; probsum[threadIdx.x] = 0.f;
  }
}

// 512 blocks x 256 threads; 16 tokens/block (4 per wave).
__global__ __launch_bounds__(256) void k_router(
    const float* __restrict__ x, const float* __restrict__ rw,
    const float* __restrict__ rb, int* __restrict__ cnt,
    int* __restrict__ tok_idx, float* __restrict__ tok_w,
    float* __restrict__ probs) {
  __shared__ float rwT[NEXP * 1024];   // [e][d], stride 1024
  const int t = threadIdx.x;
  {
    int dbase = t >> 2, e0 = (t & 3) * 4;
#pragma unroll
    for (int c = 0; c < 16; c++) {
      int d = dbase + 64 * c;
      float4 v = *(const float4*)(rw + (size_t)d * NEXP + e0);
      rwT[(e0 + 0) * 1024 + d] = v.x;
      rwT[(e0 + 1) * 1024 + d] = v.y;
      rwT[(e0 + 2) * 1024 + d] = v.z;
      rwT[(e0 + 3) * 1024 + d] = v.w;
    }
  }
  __syncthreads();
  const int lane = t & 63, wv = t >> 6;
  const int tok0 = blockIdx.x * 16 + wv * 4;
  float acc[4][NEXP];
#pragma unroll
  for (int tt = 0; tt < 4; tt++)
#pragma unroll
    for (int e = 0; e < NEXP; e++) acc[tt][e] = 0.f;

#pragma unroll
  for (int c = 0; c < 4; c++) {
    int d = lane * 4 + 256 * c;
    float4 xv[4];
#pragma unroll
    for (int tt = 0; tt < 4; tt++)
      xv[tt] = *(const float4*)(x + (size_t)(tok0 + tt) * DDIM + d);
#pragma unroll
    for (int e = 0; e < NEXP; e++) {
      float4 w4 = *(const float4*)(&rwT[e * 1024 + d]);
#pragma unroll
      for (int tt = 0; tt < 4; tt++) {
        acc[tt][e] = fmaf(xv[tt].x, w4.x, acc[tt][e]);
        acc[tt][e] = fmaf(xv[tt].y, w4.y, acc[tt][e]);
        acc[tt][e] = fmaf(xv[tt].z, w4.z, acc[tt][e]);
        acc[tt][e] = fmaf(xv[tt].w, w4.w, acc[tt][e]);
      }
    }
  }
  // full butterfly: every lane ends with all 64 sums
#pragma unroll
  for (int tt = 0; tt < 4; tt++)
#pragma unroll
    for (int e = 0; e < NEXP; e++) {
      float v = acc[tt][e];
#pragma unroll
      for (int o = 32; o; o >>= 1) v += __shfl_xor(v, o);
      acc[tt][e] = v;
    }

#pragma unroll
  for (int tt = 0; tt < 4; tt++) {
    if (lane == tt) {
      int tok = tok0 + tt;
      float mx = acc[tt][0];
#pragma unroll
      for (int e = 1; e < NEXP; e++) mx = fmaxf(mx, acc[tt][e]);
      float p[NEXP]; float s = 0.f;
#pragma unroll
      for (int e = 0; e < NEXP; e++) { p[e] = __expf(acc[tt][e] - mx); s += p[e]; }
      float inv = 1.f / s;
      float* pdst = probs + (size_t)tok * NEXP;
#pragma unroll
      for (int e = 0; e < NEXP; e++) { p[e] *= inv; pdst[e] = p[e]; }
      int i0 = 0; float b0 = acc[tt][0] + rb[0];
#pragma unroll
      for (int e = 1; e < NEXP; e++) { float v = acc[tt][e] + rb[e]; if (v > b0) { b0 = v; i0 = e; } }
      int i1 = -1; float b1 = -3.4e38f;
#pragma unroll
      for (int e = 0; e < NEXP; e++) {
        if (e == i0) continue;
        float v = acc[tt][e] + rb[e]; if (v > b1) { b1 = v; i1 = e; }
      }
      float w0 = 0.f, w1 = 0.f;
#pragma unroll
      for (int e = 0; e < NEXP; e++) { if (e == i0) w0 = p[e]; if (e == i1) w1 = p[e]; }
      float ssum = fmaxf(w0 + w1, 1e-9f);
      w0 /= ssum; w1 /= ssum;
      atomicAdd(&cnt[i0], 1); atomicAdd(&cnt[i1], 1);
      tok_idx[tok * 2]     = i0; tok_idx[tok * 2 + 1] = i1;
      tok_w[tok * 2]       = w0; tok_w[tok * 2 + 1]   = w1;
    }
  }
}

// 64 blocks: partial sums of probs -> probsum[16]
__global__ __launch_bounds__(256) void k_psum(
    const float* __restrict__ probs, float* __restrict__ probsum) {
  __shared__ float ps[NEXP];
  const int t = threadIdx.x;
  if (t < NEXP) ps[t] = 0.f;
  __syncthreads();
  int e = t & 15, trow = t >> 4;
  float s = 0.f;
#pragma unroll
  for (int c = 0; c < 8; c++) {
    int tok = blockIdx.x * 128 + c * 16 + trow;
    s += probs[(size_t)tok * NEXP + e];
  }
  atomicAdd(&ps[e], s);
  __syncthreads();
  if (t < NEXP) atomicAdd(&probsum[t], ps[t]);
}

__global__ void k_prefix(const int* __restrict__ cnt, int* __restrict__ offs) {
  if (threadIdx.x == 0) {
    int o = 0;
    for (int e = 0; e < NEXP; e++) { offs[e] = o; o += ((cnt[e] + 127) & ~127); }
    offs[NEXP] = o;
  }
}

__global__ void k_f32_to_bf16(const float* __restrict__ src,
                              unsigned short* __restrict__ dst, int n4) {
  int i = blockIdx.x * blockDim.x + threadIdx.x;
  if (i >= n4) return;
  float4 v = ((const float4*)src)[i];
  ushort4 o;
  o.x = f2bf(v.x); o.y = f2bf(v.y); o.z = f2bf(v.z); o.w = f2bf(v.w);
  ((ushort4*)dst)[i] = o;
}

// src [R][C] fp32 -> dst [C][R] bf16; 64x64 tiles
__global__ __launch_bounds__(256) void k_transpose2(
    const float* __restrict__ src, unsigned short* __restrict__ dst, int R, int C) {
  __shared__ float tile[64 * 65];   // [c][r], stride 65
  size_t mat = (size_t)blockIdx.z * R * C;
  src += mat; dst += mat;
  int tc = blockIdx.x * 64, tr = blockIdx.y * 64;
  int rx = threadIdx.x >> 4;
  int cx = (threadIdx.x & 15) * 4;
#pragma unroll
  for (int p = 0; p < 4; p++) {
    int r = p * 16 + rx;
    float4 v = *(const float4*)(src + (size_t)(tr + r) * C + tc + cx);
    tile[(cx + 0) * 65 + r] = v.x;
    tile[(cx + 1) * 65 + r] = v.y;
    tile[(cx + 2) * 65 + r] = v.z;
    tile[(cx + 3) * 65 + r] = v.w;
  }
  __syncthreads();
#pragma unroll
  for (int p = 0; p < 4; p++) {
    int c = p * 16 + rx;
    float v0 = tile[c * 65 + cx + 0];
    float v1 = tile[c * 65 + cx + 1];
    float v2 = tile[c * 65 + cx + 2];
    float v3 = tile[c * 65 + cx + 3];
    ushort4 o; o.x = f2bf(v0); o.y = f2bf(v1); o.z = f2bf(v2); o.w = f2bf(v3);
    *(ushort4*)(dst + (size_t)(tc + c) * R + tr + cx) = o;
  }
}

__global__ __launch_bounds__(256) void k_gather(
    const unsigned short* __restrict__ Xbf, const int* __restrict__ tok_idx,
    const float* __restrict__ tok_w, int* __restrict__ cursor,
    const int* __restrict__ offs, unsigned short* __restrict__ Xg,
    int* __restrict__ row_token, float* __restrict__ row_w) {
  int tok = blockIdx.x;
  __shared__ int rows[2];
  if (threadIdx.x < 2) {
    int e   = tok_idx[tok * 2 + threadIdx.x];
    int pos = atomicAdd(&cursor[e], 1);
    int row = offs[e] + pos;
    rows[threadIdx.x] = row;
    row_token[row] = tok;
    row_w[row]     = tok_w[tok * 2 + threadIdx.x];
  }
  __syncthreads();
  int slot = threadIdx.x >> 7;
  int c    = threadIdx.x & 127;
  int row  = rows[slot];
  const uint4* s = (const uint4*)(Xbf + (size_t)tok * DDIM);
  uint4* d = (uint4*)(Xg + (size_t)row * DDIM);
  d[c] = s[c];
}

// ---------------- GEMM kernels ----------------
// LDS tiles: linear [row][64] bf16 rows (128B), XOR-swizzled in 16B units:
// physical slot (r, kb) holds logical (r, kb ^ (r&7)); loaders pre-swizzle the
// GLOBAL source address (rule #21), readers XOR the ds_read address.
// Double-buffered, counted vmcnt(8), raw s_barrier.

template <bool ROUTED>
__global__ __launch_bounds__(256, 2) void k_gateup(
    const unsigned short* __restrict__ Abase,
    const unsigned short* __restrict__ BgAll,
    const unsigned short* __restrict__ BuAll,
    unsigned short* __restrict__ Hout, int Nh,
    const int* __restrict__ offs, const int* __restrict__ cnt) {
  __shared__ unsigned short As[2][TM * BK];
  __shared__ unsigned short Bgs[2][64 * BK];
  __shared__ unsigned short Bus[2][64 * BK];

  const int tm = blockIdx.x * TM;
  const int tn = blockIdx.y * 64;

  int validEnd = 0x7fffffff;
  const unsigned short* Bg = BgAll;
  const unsigned short* Bu = BuAll;
  if constexpr (ROUTED) {
    if (tm >= offs[NEXP]) return;
    int e = 0;
#pragma unroll
    for (int i = 1; i < NEXP; i++) if (tm >= offs[i]) e = i;
    validEnd = offs[e] + cnt[e];
    Bg += (size_t)e * HDIM * DDIM;
    Bu += (size_t)e * HDIM * DDIM;
  }

  const int t = threadIdx.x;
  const int lane = t & 63, wv = t >> 6;
  const unsigned short* Arow = Abase + (size_t)tm * DDIM;
  const int lr  = lane >> 3;            // row within 8-row chunk
  const int kbx = (lane & 7) ^ lr;      // pre-swizzled logical 16B-unit

  auto stage = [&](int buf, int k0) {
#pragma unroll
    for (int j = 0; j < 4; j++) {
      int ch = wv * 4 + j;
      gload16(Arow + (size_t)(ch * 8 + lr) * DDIM + k0 + kbx * 8,
              (void*)&As[buf][ch * 512]);
    }
#pragma unroll
    for (int j = 0; j < 2; j++) {
      int ch = wv * 2 + j;
      gload16(Bg + (size_t)(tn + ch * 8 + lr) * DDIM + k0 + kbx * 8,
              (void*)&Bgs[buf][ch * 512]);
      gload16(Bu + (size_t)(tn + ch * 8 + lr) * DDIM + k0 + kbx * 8,
              (void*)&Bus[buf][ch * 512]);
    }
  };

  f32x4 accG[4][2] = {};
  f32x4 accU[4][2] = {};
  const int wr = wv >> 1, wc = wv & 1;
  const int rbase = lane & 15;
  const int kgrp = lane >> 4;

  stage(0, 0);
  int cur = 0;
  for (int k0 = 0; k0 < DDIM; k0 += BK) {
    if (k0 + BK < DDIM) {
      stage(cur ^ 1, k0 + BK);
      asm volatile("s_waitcnt vmcnt(8)" ::: "memory");
    } else {
      asm volatile("s_waitcnt vmcnt(0)" ::: "memory");
    }
    __builtin_amdgcn_s_barrier();
#pragma unroll
    for (int kk = 0; kk < 2; kk++) {
      bf16x8 af[4], gf[2], uf[2];
      int kbl = kk * 4 + kgrp;
#pragma unroll
      for (int i = 0; i < 4; i++) {
        int r = wr * 64 + i * 16 + rbase;
        af[i] = *(const bf16x8*)((const char*)&As[cur][0] + r * 128 + ((kbl ^ (r & 7)) << 4));
      }
#pragma unroll
      for (int j = 0; j < 2; j++) {
        int r = wc * 32 + j * 16 + rbase;
        gf[j] = *(const bf16x8*)((const char*)&Bgs[cur][0] + r * 128 + ((kbl ^ (r & 7)) << 4));
        uf[j] = *(const bf16x8*)((const char*)&Bus[cur][0] + r * 128 + ((kbl ^ (r & 7)) << 4));
      }
#pragma unroll
      for (int i = 0; i < 4; i++)
#pragma unroll
        for (int j = 0; j < 2; j++) {
          accG[i][j] = __builtin_amdgcn_mfma_f32_16x16x32_bf16(af[i], gf[j], accG[i][j], 0, 0, 0);
          accU[i][j] = __builtin_amdgcn_mfma_f32_16x16x32_bf16(af[i], uf[j], accU[i][j], 0, 0, 0);
        }
    }
    asm volatile("s_waitcnt lgkmcnt(0)" ::: "memory");
    __builtin_amdgcn_s_barrier();
    cur ^= 1;
  }

  const int orow0 = tm + wr * 64 + (lane >> 4) * 4;
  const int ocol0 = tn + wc * 32 + (lane & 15);
#pragma unroll
  for (int i = 0; i < 4; i++)
#pragma unroll
    for (int j = 0; j < 2; j++)
#pragma unroll
      for (int r = 0; r < 4; r++) {
        int row = orow0 + i * 16 + r;
        if (row < validEnd) {
          float g = accG[i][j][r], u = accU[i][j][r];
          float h = g / (1.f + __expf(-g)) * u;
          Hout[(size_t)row * Nh + ocol0 + j * 16] = f2bf(h);
        }
      }
}

#define TND 128
template <bool ROUTED>
__global__ __launch_bounds__(256, 2) void k_down(
    const unsigned short* __restrict__ Abase,  // [Mrows][K]
    const unsigned short* __restrict__ BAll,   // [1024][K] per expert
    float* __restrict__ out,
    int K,
    const int* __restrict__ offs, const int* __restrict__ cnt,
    const int* __restrict__ row_token, const float* __restrict__ row_w) {
  __shared__ unsigned short As[2][TM * BK];
  __shared__ unsigned short Bs[2][TND * BK];

  const int tm = blockIdx.x * TM;
  const int tn = blockIdx.y * TND;

  int validEnd = 0x7fffffff;
  const unsigned short* B = BAll;
  if constexpr (ROUTED) {
    if (tm >= offs[NEXP]) return;
    int e = 0;
#pragma unroll
    for (int i = 1; i < NEXP; i++) if (tm >= offs[i]) e = i;
    validEnd = offs[e] + cnt[e];
    B += (size_t)e * DDIM * K;
  }

  const int t = threadIdx.x;
  const int lane = t & 63, wv = t >> 6;
  const unsigned short* Arow = Abase + (size_t)tm * K;
  const int lr  = lane >> 3;
  const int kbx = (lane & 7) ^ lr;

  auto stage = [&](int buf, int k0) {
#pragma unroll
    for (int j = 0; j < 4; j++) {
      int ch = wv * 4 + j;
      gload16(Arow + (size_t)(ch * 8 + lr) * K + k0 + kbx * 8,
              (void*)&As[buf][ch * 512]);
      gload16(B + (size_t)(tn + ch * 8 + lr) * K + k0 + kbx * 8,
              (void*)&Bs[buf][ch * 512]);
    }
  };

  f32x4 acc[4][4] = {};
  const int wr = wv >> 1, wc = wv & 1;
  const int rbase = lane & 15;
  const int kgrp = lane >> 4;

  stage(0, 0);
  int cur = 0;
  for (int k0 = 0; k0 < K; k0 += BK) {
    if (k0 + BK < K) {
      stage(cur ^ 1, k0 + BK);
      asm volatile("s_waitcnt vmcnt(8)" ::: "memory");
    } else {
      asm volatile("s_waitcnt vmcnt(0)" ::: "memory");
    }
    __builtin_amdgcn_s_barrier();
#pragma unroll
    for (int kk = 0; kk < 2; kk++) {
      bf16x8 af[4], bf[4];
      int kbl = kk * 4 + kgrp;
#pragma unroll
      for (int i = 0; i < 4; i++) {
        int r = wr * 64 + i * 16 + rbase;
        af[i] = *(const bf16x8*)((const char*)&As[cur][0] + r * 128 + ((kbl ^ (r & 7)) << 4));
      }
#pragma unroll
      for (int j = 0; j < 4; j++) {
        int r = wc * 64 + j * 16 + rbase;
        bf[j] = *(const bf16x8*)((const char*)&Bs[cur][0] + r * 128 + ((kbl ^ (r & 7)) << 4));
      }
#pragma unroll
      for (int i = 0; i < 4; i++)
#pragma unroll
        for (int j = 0; j < 4; j++)
          acc[i][j] = __builtin_amdgcn_mfma_f32_16x16x32_bf16(af[i], bf[j], acc[i][j], 0, 0, 0);
    }
    asm volatile("s_waitcnt lgkmcnt(0)" ::: "memory");
    __builtin_amdgcn_s_barrier();
    cur ^= 1;
  }

  const int orow0 = tm + wr * 64 + (lane >> 4) * 4;
  const int ocol0 = tn + wc * 64 + (lane & 15);
#pragma unroll
  for (int i = 0; i < 4; i++)
#pragma unroll
    for (int j = 0; j < 4; j++)
#pragma unroll
      for (int r = 0; r < 4; r++) {
        int row = orow0 + i * 16 + r;
        int col = ocol0 + j * 16;
        if constexpr (ROUTED) {
          if (row < validEnd) {
            int tok = row_token[row];
            float w = row_w[row];
            atomicAdd(&out[(size_t)tok * DDIM + col], acc[i][j][r] * w);
          }
        } else {
          out[(size_t)row * DDIM + col] = acc[i][j][r];
        }
      }
}

__global__ void k_tail(const float* __restrict__ probsum, const int* __restrict__ cnt,
                       float* __restrict__ out_tail) {
  if (threadIdx.x == 0) {
    float bal = 0.f;
    for (int e = 0; e < NEXP; e++) {
      float frac = (float)cnt[e] / (float)(N_TOK * 2);
      bal += frac * (probsum[e] / (float)N_TOK);
    }
    out_tail[0] = 0.01f * (float)NEXP * bal;
  }
  if (threadIdx.x < NEXP) out_tail[1 + threadIdx.x] = (float)cnt[threadIdx.x];
}

// ---------------- launch ----------------

extern "C" void kernel_launch(void* const* d_in, const int* in_sizes, int n_in,
                              void* d_out, int out_size, void* d_ws, size_t ws_size,
                              hipStream_t stream) {
  const float* x   = (const float*)d_in[0];
  const float* rw  = (const float*)d_in[1];
  const float* rb  = (const float*)d_in[2];
  const float* Wg  = (const float*)d_in[3];
  const float* Wu  = (const float*)d_in[4];
  const float* Wd  = (const float*)d_in[5];
  const float* sWg = (const float*)d_in[6];
  const float* sWu = (const float*)d_in[7];
  const float* sWd = (const float*)d_in[8];
  float* out = (float*)d_out;

  uint8_t* w = (uint8_t*)d_ws;
  size_t off = 0;
  auto alloc = [&](size_t bytes) -> void* {
    void* p = w + off;
    off += (bytes + 255) & ~(size_t)255;
    return p;
  };

  int*   cnt     = (int*)alloc(NEXP * 4);
  int*   cursor  = (int*)alloc(NEXP * 4);
  int*   offs    = (int*)alloc((NEXP + 1) * 4);
  float* probsum = (float*)alloc(NEXP * 4);
  int*   tok_idx = (int*)alloc((size_t)N_TOK * 2 * 4);
  float* tok_w   = (float*)alloc((size_t)N_TOK * 2 * 4);
  int*   row_tok = (int*)alloc((size_t)MT_R * TM * 4);
  float* row_w   = (float*)alloc((size_t)MT_R * TM * 4);
  float* probs   = (float*)alloc((size_t)N_TOK * NEXP * 4);
  unsigned short* Xbf  = (unsigned short*)alloc((size_t)N_TOK * DDIM * 2);
  unsigned short* Xg   = (unsigned short*)alloc((size_t)MT_R * TM * DDIM * 2);
  unsigned short* Hbuf = (unsigned short*)alloc((size_t)MT_R * TM * DDIM * 2);
  unsigned short* WgT  = (unsigned short*)alloc((size_t)NEXP * HDIM * DDIM * 2);
  unsigned short* WuT  = (unsigned short*)alloc((size_t)NEXP * HDIM * DDIM * 2);
  unsigned short* WdT  = (unsigned short*)alloc((size_t)NEXP * DDIM * HDIM * 2);
  unsigned short* sWgT = (unsigned short*)alloc((size_t)SHDIM * DDIM * 2);
  unsigned short* sWuT = (unsigned short*)alloc((size_t)SHDIM * DDIM * 2);
  unsigned short* sWdT = (unsigned short*)alloc((size_t)DDIM * SHDIM * 2);

  if (off > ws_size) return;

  k_zero<<<1, 64, 0, stream>>>(cnt, cursor, probsum);
  k_router<<<N_TOK / 16, 256, 0, stream>>>(x, rw, rb, cnt, tok_idx, tok_w, probs);
  k_psum<<<64, 256, 0, stream>>>(probs, probsum);
  k_prefix<<<1, 1, 0, stream>>>(cnt, offs);
  k_f32_to_bf16<<<(N_TOK * DDIM / 4 + 255) / 256, 256, 0, stream>>>(x, Xbf, N_TOK * DDIM / 4);

  k_transpose2<<<dim3(HDIM / 64, DDIM / 64, NEXP), 256, 0, stream>>>(Wg, WgT, DDIM, HDIM);
  k_transpose2<<<dim3(HDIM / 64, DDIM / 64, NEXP), 256, 0, stream>>>(Wu, WuT, DDIM, HDIM);
  k_transpose2<<<dim3(DDIM / 64, HDIM / 64, NEXP), 256, 0, stream>>>(Wd, WdT, HDIM, DDIM);
  k_transpose2<<<dim3(SHDIM / 64, DDIM / 64, 1), 256, 0, stream>>>(sWg, sWgT, DDIM, SHDIM);
  k_transpose2<<<dim3(SHDIM / 64, DDIM / 64, 1), 256, 0, stream>>>(sWu, sWuT, DDIM, SHDIM);
  k_transpose2<<<dim3(DDIM / 64, SHDIM / 64, 1), 256, 0, stream>>>(sWd, sWdT, SHDIM, DDIM);

  k_gather<<<N_TOK, 256, 0, stream>>>(Xbf, tok_idx, tok_w, cursor, offs, Xg, row_tok, row_w);

  // shared expert
  k_gateup<false><<<dim3(N_TOK / TM, SHDIM / 64), 256, 0, stream>>>(
      Xbf, sWgT, sWuT, Hbuf, SHDIM, nullptr, nullptr);
  k_down<false><<<dim3(N_TOK / TM, DDIM / TND), 256, 0, stream>>>(
      Hbuf, sWdT, out, SHDIM, nullptr, nullptr, nullptr, nullptr);

  // routed experts (atomic add on top of shared)
  k_gateup<true><<<dim3(MT_R, HDIM / 64), 256, 0, stream>>>(
      Xg, WgT, WuT, Hbuf, HDIM, offs, cnt);
  k_down<true><<<dim3(MT_R, DDIM / TND), 256, 0, stream>>>(
      Hbuf, WdT, out, HDIM, offs, cnt, row_tok, row_w);

  k_tail<<<1, 32, 0, stream>>>(probsum, cnt, out + (size_t)N_TOK * DDIM);
}

// Round 3
// 583.652 us; speedup vs baseline: 1.3433x; 1.0975x over previous
//
#include <hip/hip_runtime.h>
#include <stdint.h>

#define N_TOK 8192
#define DDIM  1024
#define NEXP  16
#define HDIM  1024
#define SHDIM 2048
#define TM 128
#define BK 64
#define MT_R 144       // max routed m-tiles: 16384 + 15*127 padded -> <= 18432 rows

typedef __bf16 bf16x8 __attribute__((ext_vector_type(8)));
typedef float  f32x4  __attribute__((ext_vector_type(4)));

__device__ __forceinline__ unsigned short f2bf(float f) {
  union { float f; unsigned u; } v; v.f = f;
  unsigned r = v.u + 0x7fffu + ((v.u >> 16) & 1u);
  return (unsigned short)(r >> 16);
}

__device__ __forceinline__ void gload16(const void* g, void* l) {
  __builtin_amdgcn_global_load_lds(
      (const __attribute__((address_space(1))) void*)g,
      (__attribute__((address_space(3))) void*)l, 16, 0, 0);
}

// XCD-aware bijective block swizzle: consecutive hardware blocks round-robin
// over 8 XCDs; remap so each XCD owns a contiguous chunk of work ids.
// Requires gridDim.x % 8 == 0 (all our launches satisfy this).
__device__ __forceinline__ int xcd_swizzle() {
  int nwg = (int)gridDim.x;
  int b = (int)blockIdx.x;
  return (b & 7) * (nwg >> 3) + (b >> 3);
}

// ---------------- small setup kernels ----------------

__global__ void k_zero(int* cnt, int* cursor, float* probsum) {
  if (threadIdx.x < NEXP) {
    cnt[threadIdx.x] = 0; cursor[threadIdx.x] = 0; probsum[threadIdx.x] = 0.f;
  }
}

// 512 blocks x 256 threads; 16 tokens/block (4 per wave).
__global__ __launch_bounds__(256) void k_router(
    const float* __restrict__ x, const float* __restrict__ rw,
    const float* __restrict__ rb, int* __restrict__ cnt,
    int* __restrict__ tok_idx, float* __restrict__ tok_w,
    float* __restrict__ probs) {
  __shared__ float rwT[NEXP * 1024];   // [e][d], stride 1024
  const int t = threadIdx.x;
  {
    int dbase = t >> 2, e0 = (t & 3) * 4;
#pragma unroll
    for (int c = 0; c < 16; c++) {
      int d = dbase + 64 * c;
      float4 v = *(const float4*)(rw + (size_t)d * NEXP + e0);
      rwT[(e0 + 0) * 1024 + d] = v.x;
      rwT[(e0 + 1) * 1024 + d] = v.y;
      rwT[(e0 + 2) * 1024 + d] = v.z;
      rwT[(e0 + 3) * 1024 + d] = v.w;
    }
  }
  __syncthreads();
  const int lane = t & 63, wv = t >> 6;
  const int tok0 = blockIdx.x * 16 + wv * 4;
  float acc[4][NEXP];
#pragma unroll
  for (int tt = 0; tt < 4; tt++)
#pragma unroll
    for (int e = 0; e < NEXP; e++) acc[tt][e] = 0.f;

#pragma unroll
  for (int c = 0; c < 4; c++) {
    int d = lane * 4 + 256 * c;
    float4 xv[4];
#pragma unroll
    for (int tt = 0; tt < 4; tt++)
      xv[tt] = *(const float4*)(x + (size_t)(tok0 + tt) * DDIM + d);
#pragma unroll
    for (int e = 0; e < NEXP; e++) {
      float4 w4 = *(const float4*)(&rwT[e * 1024 + d]);
#pragma unroll
      for (int tt = 0; tt < 4; tt++) {
        acc[tt][e] = fmaf(xv[tt].x, w4.x, acc[tt][e]);
        acc[tt][e] = fmaf(xv[tt].y, w4.y, acc[tt][e]);
        acc[tt][e] = fmaf(xv[tt].z, w4.z, acc[tt][e]);
        acc[tt][e] = fmaf(xv[tt].w, w4.w, acc[tt][e]);
      }
    }
  }
#pragma unroll
  for (int tt = 0; tt < 4; tt++)
#pragma unroll
    for (int e = 0; e < NEXP; e++) {
      float v = acc[tt][e];
#pragma unroll
      for (int o = 32; o; o >>= 1) v += __shfl_xor(v, o);
      acc[tt][e] = v;
    }

#pragma unroll
  for (int tt = 0; tt < 4; tt++) {
    if (lane == tt) {
      int tok = tok0 + tt;
      float mx = acc[tt][0];
#pragma unroll
      for (int e = 1; e < NEXP; e++) mx = fmaxf(mx, acc[tt][e]);
      float p[NEXP]; float s = 0.f;
#pragma unroll
      for (int e = 0; e < NEXP; e++) { p[e] = __expf(acc[tt][e] - mx); s += p[e]; }
      float inv = 1.f / s;
      float* pdst = probs + (size_t)tok * NEXP;
#pragma unroll
      for (int e = 0; e < NEXP; e++) { p[e] *= inv; pdst[e] = p[e]; }
      int i0 = 0; float b0 = acc[tt][0] + rb[0];
#pragma unroll
      for (int e = 1; e < NEXP; e++) { float v = acc[tt][e] + rb[e]; if (v > b0) { b0 = v; i0 = e; } }
      int i1 = -1; float b1 = -3.4e38f;
#pragma unroll
      for (int e = 0; e < NEXP; e++) {
        if (e == i0) continue;
        float v = acc[tt][e] + rb[e]; if (v > b1) { b1 = v; i1 = e; }
      }
      float w0 = 0.f, w1 = 0.f;
#pragma unroll
      for (int e = 0; e < NEXP; e++) { if (e == i0) w0 = p[e]; if (e == i1) w1 = p[e]; }
      float ssum = fmaxf(w0 + w1, 1e-9f);
      w0 /= ssum; w1 /= ssum;
      atomicAdd(&cnt[i0], 1); atomicAdd(&cnt[i1], 1);
      tok_idx[tok * 2]     = i0; tok_idx[tok * 2 + 1] = i1;
      tok_w[tok * 2]       = w0; tok_w[tok * 2 + 1]   = w1;
    }
  }
}

__global__ __launch_bounds__(256) void k_psum(
    const float* __restrict__ probs, float* __restrict__ probsum) {
  __shared__ float ps[NEXP];
  const int t = threadIdx.x;
  if (t < NEXP) ps[t] = 0.f;
  __syncthreads();
  int e = t & 15, trow = t >> 4;
  float s = 0.f;
#pragma unroll
  for (int c = 0; c < 8; c++) {
    int tok = blockIdx.x * 128 + c * 16 + trow;
    s += probs[(size_t)tok * NEXP + e];
  }
  atomicAdd(&ps[e], s);
  __syncthreads();
  if (t < NEXP) atomicAdd(&probsum[t], ps[t]);
}

__global__ void k_prefix(const int* __restrict__ cnt, int* __restrict__ offs) {
  if (threadIdx.x == 0) {
    int o = 0;
    for (int e = 0; e < NEXP; e++) { offs[e] = o; o += ((cnt[e] + 127) & ~127); }
    offs[NEXP] = o;
  }
}

__global__ void k_f32_to_bf16(const float* __restrict__ src,
                              unsigned short* __restrict__ dst, int n4) {
  int i = blockIdx.x * blockDim.x + threadIdx.x;
  if (i >= n4) return;
  float4 v = ((const float4*)src)[i];
  ushort4 o;
  o.x = f2bf(v.x); o.y = f2bf(v.y); o.z = f2bf(v.z); o.w = f2bf(v.w);
  ((ushort4*)dst)[i] = o;
}

// src [R][C] fp32 -> dst [C][R] bf16; 64x64 tiles
__global__ __launch_bounds__(256) void k_transpose2(
    const float* __restrict__ src, unsigned short* __restrict__ dst, int R, int C) {
  __shared__ float tile[64 * 65];
  size_t mat = (size_t)blockIdx.z * R * C;
  src += mat; dst += mat;
  int tc = blockIdx.x * 64, tr = blockIdx.y * 64;
  int rx = threadIdx.x >> 4;
  int cx = (threadIdx.x & 15) * 4;
#pragma unroll
  for (int p = 0; p < 4; p++) {
    int r = p * 16 + rx;
    float4 v = *(const float4*)(src + (size_t)(tr + r) * C + tc + cx);
    tile[(cx + 0) * 65 + r] = v.x;
    tile[(cx + 1) * 65 + r] = v.y;
    tile[(cx + 2) * 65 + r] = v.z;
    tile[(cx + 3) * 65 + r] = v.w;
  }
  __syncthreads();
#pragma unroll
  for (int p = 0; p < 4; p++) {
    int c = p * 16 + rx;
    float v0 = tile[c * 65 + cx + 0];
    float v1 = tile[c * 65 + cx + 1];
    float v2 = tile[c * 65 + cx + 2];
    float v3 = tile[c * 65 + cx + 3];
    ushort4 o; o.x = f2bf(v0); o.y = f2bf(v1); o.z = f2bf(v2); o.w = f2bf(v3);
    *(ushort4*)(dst + (size_t)(tc + c) * R + tr + cx) = o;
  }
}

__global__ __launch_bounds__(256) void k_gather(
    const unsigned short* __restrict__ Xbf, const int* __restrict__ tok_idx,
    const float* __restrict__ tok_w, int* __restrict__ cursor,
    const int* __restrict__ offs, unsigned short* __restrict__ Xg,
    int* __restrict__ row_token, float* __restrict__ row_w) {
  int tok = blockIdx.x;
  __shared__ int rows[2];
  if (threadIdx.x < 2) {
    int e   = tok_idx[tok * 2 + threadIdx.x];
    int pos = atomicAdd(&cursor[e], 1);
    int row = offs[e] + pos;
    rows[threadIdx.x] = row;
    row_token[row] = tok;
    row_w[row]     = tok_w[tok * 2 + threadIdx.x];
  }
  __syncthreads();
  int slot = threadIdx.x >> 7;
  int c    = threadIdx.x & 127;
  int row  = rows[slot];
  const uint4* s = (const uint4*)(Xbf + (size_t)tok * DDIM);
  uint4* d = (uint4*)(Xg + (size_t)row * DDIM);
  d[c] = s[c];
}

// ---------------- GEMM kernels (m97 structure) ----------------
// Single-buffered 32KB LDS, 2-barrier K-loop, global_load_lds width 16,
// 16B-unit XOR swizzle (pre-swizzled global source + swizzled ds_read),
// XCD-aware block swizzle, mt-major decode (nt sweeps fastest within an XCD).

template <bool ROUTED, int NT>
__global__ __launch_bounds__(256, 4) void k_gateup(
    const unsigned short* __restrict__ Abase,
    const unsigned short* __restrict__ BgAll,
    const unsigned short* __restrict__ BuAll,
    unsigned short* __restrict__ Hout, int Nh,
    const int* __restrict__ offs, const int* __restrict__ cnt) {
  __shared__ unsigned short As[TM * BK];
  __shared__ unsigned short Bgs[64 * BK];
  __shared__ unsigned short Bus[64 * BK];

  const int wg = xcd_swizzle();
  const int tm = (wg / NT) * TM;
  const int tn = (wg % NT) * 64;

  int validEnd = 0x7fffffff;
  const unsigned short* Bg = BgAll;
  const unsigned short* Bu = BuAll;
  if constexpr (ROUTED) {
    if (tm >= offs[NEXP]) return;
    int e = 0;
#pragma unroll
    for (int i = 1; i < NEXP; i++) if (tm >= offs[i]) e = i;
    validEnd = offs[e] + cnt[e];
    Bg += (size_t)e * HDIM * DDIM;
    Bu += (size_t)e * HDIM * DDIM;
  }

  const int t = threadIdx.x;
  const int lane = t & 63, wv = t >> 6;
  const unsigned short* Arow = Abase + (size_t)tm * DDIM;
  const int lr  = lane >> 3;            // row within 8-row chunk
  const int kbx = (lane & 7) ^ lr;      // pre-swizzled 16B-unit column

  auto stage = [&](int k0) {
#pragma unroll
    for (int j = 0; j < 4; j++) {
      int ch = wv * 4 + j;
      gload16(Arow + (size_t)(ch * 8 + lr) * DDIM + k0 + kbx * 8, (void*)&As[ch * 512]);
    }
#pragma unroll
    for (int j = 0; j < 2; j++) {
      int ch = wv * 2 + j;
      gload16(Bg + (size_t)(tn + ch * 8 + lr) * DDIM + k0 + kbx * 8, (void*)&Bgs[ch * 512]);
      gload16(Bu + (size_t)(tn + ch * 8 + lr) * DDIM + k0 + kbx * 8, (void*)&Bus[ch * 512]);
    }
  };

  f32x4 accG[4][2] = {};
  f32x4 accU[4][2] = {};
  const int wr = wv >> 1, wc = wv & 1;
  const int rbase = lane & 15;
  const int kgrp = lane >> 4;

  for (int k0 = 0; k0 < DDIM; k0 += BK) {
    if (k0) __syncthreads();
    stage(k0);
    __syncthreads();
#pragma unroll
    for (int kk = 0; kk < 2; kk++) {
      bf16x8 af[4], gf[2], uf[2];
      int kbl = kk * 4 + kgrp;
#pragma unroll
      for (int i = 0; i < 4; i++) {
        int r = wr * 64 + i * 16 + rbase;
        af[i] = *(const bf16x8*)((const char*)&As[0] + r * 128 + ((kbl ^ (r & 7)) << 4));
      }
#pragma unroll
      for (int j = 0; j < 2; j++) {
        int r = wc * 32 + j * 16 + rbase;
        gf[j] = *(const bf16x8*)((const char*)&Bgs[0] + r * 128 + ((kbl ^ (r & 7)) << 4));
        uf[j] = *(const bf16x8*)((const char*)&Bus[0] + r * 128 + ((kbl ^ (r & 7)) << 4));
      }
#pragma unroll
      for (int i = 0; i < 4; i++)
#pragma unroll
        for (int j = 0; j < 2; j++) {
          accG[i][j] = __builtin_amdgcn_mfma_f32_16x16x32_bf16(af[i], gf[j], accG[i][j], 0, 0, 0);
          accU[i][j] = __builtin_amdgcn_mfma_f32_16x16x32_bf16(af[i], uf[j], accU[i][j], 0, 0, 0);
        }
    }
  }

  const int orow0 = tm + wr * 64 + (lane >> 4) * 4;
  const int ocol0 = tn + wc * 32 + (lane & 15);
#pragma unroll
  for (int i = 0; i < 4; i++)
#pragma unroll
    for (int j = 0; j < 2; j++)
#pragma unroll
      for (int r = 0; r < 4; r++) {
        int row = orow0 + i * 16 + r;
        if (row < validEnd) {
          float g = accG[i][j][r], u = accU[i][j][r];
          float h = g / (1.f + __expf(-g)) * u;
          Hout[(size_t)row * Nh + ocol0 + j * 16] = f2bf(h);
        }
      }
}

#define TND 128
template <bool ROUTED, int NT>
__global__ __launch_bounds__(256, 4) void k_down(
    const unsigned short* __restrict__ Abase,  // [Mrows][K]
    const unsigned short* __restrict__ BAll,   // [1024][K] per expert
    float* __restrict__ out,
    int K,
    const int* __restrict__ offs, const int* __restrict__ cnt,
    const int* __restrict__ row_token, const float* __restrict__ row_w) {
  __shared__ unsigned short As[TM * BK];
  __shared__ unsigned short Bs[TND * BK];

  const int wg = xcd_swizzle();
  const int tm = (wg / NT) * TM;
  const int tn = (wg % NT) * TND;

  int validEnd = 0x7fffffff;
  const unsigned short* B = BAll;
  if constexpr (ROUTED) {
    if (tm >= offs[NEXP]) return;
    int e = 0;
#pragma unroll
    for (int i = 1; i < NEXP; i++) if (tm >= offs[i]) e = i;
    validEnd = offs[e] + cnt[e];
    B += (size_t)e * DDIM * K;
  }

  const int t = threadIdx.x;
  const int lane = t & 63, wv = t >> 6;
  const unsigned short* Arow = Abase + (size_t)tm * K;
  const int lr  = lane >> 3;
  const int kbx = (lane & 7) ^ lr;

  auto stage = [&](int k0) {
#pragma unroll
    for (int j = 0; j < 4; j++) {
      int ch = wv * 4 + j;
      gload16(Arow + (size_t)(ch * 8 + lr) * K + k0 + kbx * 8, (void*)&As[ch * 512]);
      gload16(B + (size_t)(tn + ch * 8 + lr) * K + k0 + kbx * 8, (void*)&Bs[ch * 512]);
    }
  };

  f32x4 acc[4][4] = {};
  const int wr = wv >> 1, wc = wv & 1;
  const int rbase = lane & 15;
  const int kgrp = lane >> 4;

  for (int k0 = 0; k0 < K; k0 += BK) {
    if (k0) __syncthreads();
    stage(k0);
    __syncthreads();
#pragma unroll
    for (int kk = 0; kk < 2; kk++) {
      bf16x8 af[4], bf[4];
      int kbl = kk * 4 + kgrp;
#pragma unroll
      for (int i = 0; i < 4; i++) {
        int r = wr * 64 + i * 16 + rbase;
        af[i] = *(const bf16x8*)((const char*)&As[0] + r * 128 + ((kbl ^ (r & 7)) << 4));
      }
#pragma unroll
      for (int j = 0; j < 4; j++) {
        int r = wc * 64 + j * 16 + rbase;
        bf[j] = *(const bf16x8*)((const char*)&Bs[0] + r * 128 + ((kbl ^ (r & 7)) << 4));
      }
#pragma unroll
      for (int i = 0; i < 4; i++)
#pragma unroll
        for (int j = 0; j < 4; j++)
          acc[i][j] = __builtin_amdgcn_mfma_f32_16x16x32_bf16(af[i], bf[j], acc[i][j], 0, 0, 0);
    }
  }

  const int orow0 = tm + wr * 64 + (lane >> 4) * 4;
  const int ocol0 = tn + wc * 64 + (lane & 15);
#pragma unroll
  for (int i = 0; i < 4; i++)
#pragma unroll
    for (int j = 0; j < 4; j++)
#pragma unroll
      for (int r = 0; r < 4; r++) {
        int row = orow0 + i * 16 + r;
        int col = ocol0 + j * 16;
        if constexpr (ROUTED) {
          if (row < validEnd) {
            int tok = row_token[row];
            float w = row_w[row];
            atomicAdd(&out[(size_t)tok * DDIM + col], acc[i][j][r] * w);
          }
        } else {
          out[(size_t)row * DDIM + col] = acc[i][j][r];
        }
      }
}

__global__ void k_tail(const float* __restrict__ probsum, const int* __restrict__ cnt,
                       float* __restrict__ out_tail) {
  if (threadIdx.x == 0) {
    float bal = 0.f;
    for (int e = 0; e < NEXP; e++) {
      float frac = (float)cnt[e] / (float)(N_TOK * 2);
      bal += frac * (probsum[e] / (float)N_TOK);
    }
    out_tail[0] = 0.01f * (float)NEXP * bal;
  }
  if (threadIdx.x < NEXP) out_tail[1 + threadIdx.x] = (float)cnt[threadIdx.x];
}

// ---------------- launch ----------------

extern "C" void kernel_launch(void* const* d_in, const int* in_sizes, int n_in,
                              void* d_out, int out_size, void* d_ws, size_t ws_size,
                              hipStream_t stream) {
  const float* x   = (const float*)d_in[0];
  const float* rw  = (const float*)d_in[1];
  const float* rb  = (const float*)d_in[2];
  const float* Wg  = (const float*)d_in[3];
  const float* Wu  = (const float*)d_in[4];
  const float* Wd  = (const float*)d_in[5];
  const float* sWg = (const float*)d_in[6];
  const float* sWu = (const float*)d_in[7];
  const float* sWd = (const float*)d_in[8];
  float* out = (float*)d_out;

  uint8_t* w = (uint8_t*)d_ws;
  size_t off = 0;
  auto alloc = [&](size_t bytes) -> void* {
    void* p = w + off;
    off += (bytes + 255) & ~(size_t)255;
    return p;
  };

  int*   cnt     = (int*)alloc(NEXP * 4);
  int*   cursor  = (int*)alloc(NEXP * 4);
  int*   offs    = (int*)alloc((NEXP + 1) * 4);
  float* probsum = (float*)alloc(NEXP * 4);
  int*   tok_idx = (int*)alloc((size_t)N_TOK * 2 * 4);
  float* tok_w   = (float*)alloc((size_t)N_TOK * 2 * 4);
  int*   row_tok = (int*)alloc((size_t)MT_R * TM * 4);
  float* row_w   = (float*)alloc((size_t)MT_R * TM * 4);
  float* probs   = (float*)alloc((size_t)N_TOK * NEXP * 4);
  unsigned short* Xbf  = (unsigned short*)alloc((size_t)N_TOK * DDIM * 2);
  unsigned short* Xg   = (unsigned short*)alloc((size_t)MT_R * TM * DDIM * 2);
  unsigned short* Hbuf = (unsigned short*)alloc((size_t)MT_R * TM * DDIM * 2);
  unsigned short* WgT  = (unsigned short*)alloc((size_t)NEXP * HDIM * DDIM * 2);
  unsigned short* WuT  = (unsigned short*)alloc((size_t)NEXP * HDIM * DDIM * 2);
  unsigned short* WdT  = (unsigned short*)alloc((size_t)NEXP * DDIM * HDIM * 2);
  unsigned short* sWgT = (unsigned short*)alloc((size_t)SHDIM * DDIM * 2);
  unsigned short* sWuT = (unsigned short*)alloc((size_t)SHDIM * DDIM * 2);
  unsigned short* sWdT = (unsigned short*)alloc((size_t)DDIM * SHDIM * 2);

  if (off > ws_size) return;

  k_zero<<<1, 64, 0, stream>>>(cnt, cursor, probsum);
  k_router<<<N_TOK / 16, 256, 0, stream>>>(x, rw, rb, cnt, tok_idx, tok_w, probs);
  k_psum<<<64, 256, 0, stream>>>(probs, probsum);
  k_prefix<<<1, 1, 0, stream>>>(cnt, offs);
  k_f32_to_bf16<<<(N_TOK * DDIM / 4 + 255) / 256, 256, 0, stream>>>(x, Xbf, N_TOK * DDIM / 4);

  k_transpose2<<<dim3(HDIM / 64, DDIM / 64, NEXP), 256, 0, stream>>>(Wg, WgT, DDIM, HDIM);
  k_transpose2<<<dim3(HDIM / 64, DDIM / 64, NEXP), 256, 0, stream>>>(Wu, WuT, DDIM, HDIM);
  k_transpose2<<<dim3(DDIM / 64, HDIM / 64, NEXP), 256, 0, stream>>>(Wd, WdT, HDIM, DDIM);
  k_transpose2<<<dim3(SHDIM / 64, DDIM / 64, 1), 256, 0, stream>>>(sWg, sWgT, DDIM, SHDIM);
  k_transpose2<<<dim3(SHDIM / 64, DDIM / 64, 1), 256, 0, stream>>>(sWu, sWuT, DDIM, SHDIM);
  k_transpose2<<<dim3(DDIM / 64, SHDIM / 64, 1), 256, 0, stream>>>(sWd, sWdT, SHDIM, DDIM);

  k_gather<<<N_TOK, 256, 0, stream>>>(Xbf, tok_idx, tok_w, cursor, offs, Xg, row_tok, row_w);

  // shared expert
  k_gateup<false, SHDIM / 64><<<(N_TOK / TM) * (SHDIM / 64), 256, 0, stream>>>(
      Xbf, sWgT, sWuT, Hbuf, SHDIM, nullptr, nullptr);
  k_down<false, DDIM / TND><<<(N_TOK / TM) * (DDIM / TND), 256, 0, stream>>>(
      Hbuf, sWdT, out, SHDIM, nullptr, nullptr, nullptr, nullptr);

  // routed experts (atomic add on top of shared)
  k_gateup<true, HDIM / 64><<<MT_R * (HDIM / 64), 256, 0, stream>>>(
      Xg, WgT, WuT, Hbuf, HDIM, offs, cnt);
  k_down<true, DDIM / TND><<<MT_R * (DDIM / TND), 256, 0, stream>>>(
      Hbuf, WdT, out, HDIM, offs, cnt, row_tok, row_w);

  k_tail<<<1, 32, 0, stream>>>(probsum, cnt, out + (size_t)N_TOK * DDIM);
}

// Round 4
// 472.682 us; speedup vs baseline: 1.6587x; 1.2348x over previous
//
#include <hip/hip_runtime.h>
#include <stdint.h>

#define N_TOK 8192
#define DDIM  1024
#define NEXP  16
#define HDIM  1024
#define SHDIM 2048
#define TM 128
#define BK 64
#define MT_R 144       // max routed m-tiles: 16384 + 15*127 padded -> <= 18432 rows

// merged grid geometry
#define SH_GU_NT  (SHDIM / 64)                 // 32
#define SH_GU_WGS ((N_TOK / TM) * SH_GU_NT)    // 2048
#define RT_GU_NT  (HDIM / 64)                  // 16
#define RT_GU_WGS (MT_R * RT_GU_NT)            // 2304
#define GU_WGS    (SH_GU_WGS + RT_GU_WGS)      // 4352  (%8==0)

#define TND 128
#define DN_NT     (DDIM / TND)                 // 8
#define SH_DN_WGS ((N_TOK / TM) * DN_NT)       // 512
#define RT_DN_WGS (MT_R * DN_NT)               // 1152
#define DN_WGS    (SH_DN_WGS + RT_DN_WGS)      // 1664  (%8==0)

#define CPAD 16   // counter padding: one 64B line per counter

typedef __bf16 bf16x8 __attribute__((ext_vector_type(8)));
typedef float  f32x4  __attribute__((ext_vector_type(4)));

__device__ __forceinline__ unsigned short f2bf(float f) {
  union { float f; unsigned u; } v; v.f = f;
  unsigned r = v.u + 0x7fffu + ((v.u >> 16) & 1u);
  return (unsigned short)(r >> 16);
}

__device__ __forceinline__ void gload16(const void* g, void* l) {
  __builtin_amdgcn_global_load_lds(
      (const __attribute__((address_space(1))) void*)g,
      (__attribute__((address_space(3))) void*)l, 16, 0, 0);
}

// XCD-aware bijective block swizzle (requires gridDim.x % 8 == 0).
__device__ __forceinline__ int xcd_swizzle() {
  int nwg = (int)gridDim.x;
  int b = (int)blockIdx.x;
  return (b & 7) * (nwg >> 3) + (b >> 3);
}

// ---------------- small setup kernels ----------------

__global__ void k_zero(int* cnt, int* cursor, float* probsum) {
  int t = threadIdx.x;
  if (t < NEXP * CPAD) { cnt[t] = 0; cursor[t] = 0; probsum[t] = 0.f; }
}

// 512 blocks x 256 threads; 16 tokens/block (4 per wave).
__global__ __launch_bounds__(256) void k_router(
    const float* __restrict__ x, const float* __restrict__ rw,
    const float* __restrict__ rb, int* __restrict__ cnt,
    int* __restrict__ tok_idx, float* __restrict__ tok_w,
    float* __restrict__ probs) {
  __shared__ float rwT[NEXP * 1024];
  const int t = threadIdx.x;
  {
    int dbase = t >> 2, e0 = (t & 3) * 4;
#pragma unroll
    for (int c = 0; c < 16; c++) {
      int d = dbase + 64 * c;
      float4 v = *(const float4*)(rw + (size_t)d * NEXP + e0);
      rwT[(e0 + 0) * 1024 + d] = v.x;
      rwT[(e0 + 1) * 1024 + d] = v.y;
      rwT[(e0 + 2) * 1024 + d] = v.z;
      rwT[(e0 + 3) * 1024 + d] = v.w;
    }
  }
  __syncthreads();
  const int lane = t & 63, wv = t >> 6;
  const int tok0 = blockIdx.x * 16 + wv * 4;
  float acc[4][NEXP];
#pragma unroll
  for (int tt = 0; tt < 4; tt++)
#pragma unroll
    for (int e = 0; e < NEXP; e++) acc[tt][e] = 0.f;

#pragma unroll
  for (int c = 0; c < 4; c++) {
    int d = lane * 4 + 256 * c;
    float4 xv[4];
#pragma unroll
    for (int tt = 0; tt < 4; tt++)
      xv[tt] = *(const float4*)(x + (size_t)(tok0 + tt) * DDIM + d);
#pragma unroll
    for (int e = 0; e < NEXP; e++) {
      float4 w4 = *(const float4*)(&rwT[e * 1024 + d]);
#pragma unroll
      for (int tt = 0; tt < 4; tt++) {
        acc[tt][e] = fmaf(xv[tt].x, w4.x, acc[tt][e]);
        acc[tt][e] = fmaf(xv[tt].y, w4.y, acc[tt][e]);
        acc[tt][e] = fmaf(xv[tt].z, w4.z, acc[tt][e]);
        acc[tt][e] = fmaf(xv[tt].w, w4.w, acc[tt][e]);
      }
    }
  }
#pragma unroll
  for (int tt = 0; tt < 4; tt++)
#pragma unroll
    for (int e = 0; e < NEXP; e++) {
      float v = acc[tt][e];
#pragma unroll
      for (int o = 32; o; o >>= 1) v += __shfl_xor(v, o);
      acc[tt][e] = v;
    }

#pragma unroll
  for (int tt = 0; tt < 4; tt++) {
    if (lane == tt) {
      int tok = tok0 + tt;
      float mx = acc[tt][0];
#pragma unroll
      for (int e = 1; e < NEXP; e++) mx = fmaxf(mx, acc[tt][e]);
      float p[NEXP]; float s = 0.f;
#pragma unroll
      for (int e = 0; e < NEXP; e++) { p[e] = __expf(acc[tt][e] - mx); s += p[e]; }
      float inv = 1.f / s;
      float* pdst = probs + (size_t)tok * NEXP;
#pragma unroll
      for (int e = 0; e < NEXP; e++) { p[e] *= inv; pdst[e] = p[e]; }
      int i0 = 0; float b0 = acc[tt][0] + rb[0];
#pragma unroll
      for (int e = 1; e < NEXP; e++) { float v = acc[tt][e] + rb[e]; if (v > b0) { b0 = v; i0 = e; } }
      int i1 = -1; float b1 = -3.4e38f;
#pragma unroll
      for (int e = 0; e < NEXP; e++) {
        if (e == i0) continue;
        float v = acc[tt][e] + rb[e]; if (v > b1) { b1 = v; i1 = e; }
      }
      float w0 = 0.f, w1 = 0.f;
#pragma unroll
      for (int e = 0; e < NEXP; e++) { if (e == i0) w0 = p[e]; if (e == i1) w1 = p[e]; }
      float ssum = fmaxf(w0 + w1, 1e-9f);
      w0 /= ssum; w1 /= ssum;
      atomicAdd(&cnt[i0 * CPAD], 1); atomicAdd(&cnt[i1 * CPAD], 1);
      tok_idx[tok * 2]     = i0; tok_idx[tok * 2 + 1] = i1;
      tok_w[tok * 2]       = w0; tok_w[tok * 2 + 1]   = w1;
    }
  }
}

__global__ __launch_bounds__(256) void k_psum(
    const float* __restrict__ probs, float* __restrict__ probsum) {
  __shared__ float ps[NEXP];
  const int t = threadIdx.x;
  if (t < NEXP) ps[t] = 0.f;
  __syncthreads();
  int e = t & 15, trow = t >> 4;
  float s = 0.f;
#pragma unroll
  for (int c = 0; c < 8; c++) {
    int tok = blockIdx.x * 128 + c * 16 + trow;
    s += probs[(size_t)tok * NEXP + e];
  }
  atomicAdd(&ps[e], s);
  __syncthreads();
  if (t < NEXP) atomicAdd(&probsum[t * CPAD], ps[t]);
}

__global__ void k_prefix(const int* __restrict__ cnt, int* __restrict__ offs) {
  if (threadIdx.x == 0) {
    int o = 0;
    for (int e = 0; e < NEXP; e++) { offs[e] = o; o += ((cnt[e * CPAD] + 127) & ~127); }
    offs[NEXP] = o;
  }
}

// one thread per (token, k) slot: assign routed row, record token + weight
__global__ __launch_bounds__(256) void k_assign(
    const int* __restrict__ tok_idx, const float* __restrict__ tok_w,
    int* __restrict__ cursor, const int* __restrict__ offs,
    int* __restrict__ row_token, float* __restrict__ row_w) {
  int i = blockIdx.x * 256 + threadIdx.x;
  if (i >= N_TOK * 2) return;
  int e = tok_idx[i];
  int pos = atomicAdd(&cursor[e * CPAD], 1);
  int row = offs[e] + pos;
  row_token[row] = i >> 1;
  row_w[row] = tok_w[i];
}

__global__ void k_f32_to_bf16(const float* __restrict__ src,
                              unsigned short* __restrict__ dst, int n4) {
  int i = blockIdx.x * blockDim.x + threadIdx.x;
  if (i >= n4) return;
  float4 v = ((const float4*)src)[i];
  ushort4 o;
  o.x = f2bf(v.x); o.y = f2bf(v.y); o.z = f2bf(v.z); o.w = f2bf(v.w);
  ((ushort4*)dst)[i] = o;
}

// src [R][C] fp32 -> dst [C][R] bf16; 64x64 tiles
__global__ __launch_bounds__(256) void k_transpose2(
    const float* __restrict__ src, unsigned short* __restrict__ dst, int R, int C) {
  __shared__ float tile[64 * 65];
  size_t mat = (size_t)blockIdx.z * R * C;
  src += mat; dst += mat;
  int tc = blockIdx.x * 64, tr = blockIdx.y * 64;
  int rx = threadIdx.x >> 4;
  int cx = (threadIdx.x & 15) * 4;
#pragma unroll
  for (int p = 0; p < 4; p++) {
    int r = p * 16 + rx;
    float4 v = *(const float4*)(src + (size_t)(tr + r) * C + tc + cx);
    tile[(cx + 0) * 65 + r] = v.x;
    tile[(cx + 1) * 65 + r] = v.y;
    tile[(cx + 2) * 65 + r] = v.z;
    tile[(cx + 3) * 65 + r] = v.w;
  }
  __syncthreads();
#pragma unroll
  for (int p = 0; p < 4; p++) {
    int c = p * 16 + rx;
    float v0 = tile[c * 65 + cx + 0];
    float v1 = tile[c * 65 + cx + 1];
    float v2 = tile[c * 65 + cx + 2];
    float v3 = tile[c * 65 + cx + 3];
    ushort4 o; o.x = f2bf(v0); o.y = f2bf(v1); o.z = f2bf(v2); o.w = f2bf(v3);
    *(ushort4*)(dst + (size_t)(tc + c) * R + tr + cx) = o;
  }
}

// ---------------- merged GEMM kernels (m97 structure) ----------------
// Single-buffered 32KB LDS, 2-barrier K-loop, global_load_lds width 16,
// 16B-unit XOR swizzle (pre-swizzled global source + swizzled ds_read),
// XCD-aware block swizzle. One launch covers shared + routed segments.

__global__ __launch_bounds__(256, 4) void k_gateup_all(
    const unsigned short* __restrict__ Xbf,
    const unsigned short* __restrict__ sWgT,
    const unsigned short* __restrict__ sWuT,
    const unsigned short* __restrict__ WgT,
    const unsigned short* __restrict__ WuT,
    unsigned short* __restrict__ Hs,
    unsigned short* __restrict__ Hr,
    const int* __restrict__ offs, const int* __restrict__ cnt,
    const int* __restrict__ row_token) {
  __shared__ unsigned short As[TM * BK];
  __shared__ unsigned short Bgs[64 * BK];
  __shared__ unsigned short Bus[64 * BK];

  const int wg = xcd_swizzle();
  const int t = threadIdx.x;
  const int lane = t & 63, wv = t >> 6;
  const int lr  = lane >> 3;            // row within 8-row chunk
  const int kbx = (lane & 7) ^ lr;      // pre-swizzled 16B-unit column

  int tm, tn, validEnd, Nh;
  const unsigned short *Bgp, *Bup;
  unsigned short* Hout;
  const unsigned short* pA[4];

  if (wg < SH_GU_WGS) {
    tm = (wg / SH_GU_NT) * TM;
    tn = (wg % SH_GU_NT) * 64;
    validEnd = 0x7fffffff;
    Bgp = sWgT; Bup = sWuT;
    Hout = Hs; Nh = SHDIM;
#pragma unroll
    for (int j = 0; j < 4; j++)
      pA[j] = Xbf + (size_t)(tm + (wv * 4 + j) * 8 + lr) * DDIM;
  } else {
    int wgr = wg - SH_GU_WGS;
    tm = (wgr / RT_GU_NT) * TM;
    tn = (wgr % RT_GU_NT) * 64;
    if (tm >= offs[NEXP]) return;
    int e = 0;
#pragma unroll
    for (int i = 1; i < NEXP; i++) if (tm >= offs[i]) e = i;
    validEnd = offs[e] + cnt[e * CPAD];
    Bgp = WgT + (size_t)e * HDIM * DDIM;
    Bup = WuT + (size_t)e * HDIM * DDIM;
    Hout = Hr; Nh = HDIM;
#pragma unroll
    for (int j = 0; j < 4; j++) {
      int row = tm + (wv * 4 + j) * 8 + lr;
      int tok = row < validEnd ? row_token[row] : 0;
      pA[j] = Xbf + (size_t)tok * DDIM;
    }
  }
  const unsigned short* pBg[2];
  const unsigned short* pBu[2];
#pragma unroll
  for (int j = 0; j < 2; j++) {
    int row = tn + (wv * 2 + j) * 8 + lr;
    pBg[j] = Bgp + (size_t)row * DDIM;
    pBu[j] = Bup + (size_t)row * DDIM;
  }

  auto stage = [&](int k0) {
#pragma unroll
    for (int j = 0; j < 4; j++)
      gload16(pA[j] + k0 + kbx * 8, (void*)&As[(wv * 4 + j) * 512]);
#pragma unroll
    for (int j = 0; j < 2; j++) {
      gload16(pBg[j] + k0 + kbx * 8, (void*)&Bgs[(wv * 2 + j) * 512]);
      gload16(pBu[j] + k0 + kbx * 8, (void*)&Bus[(wv * 2 + j) * 512]);
    }
  };

  f32x4 accG[4][2] = {};
  f32x4 accU[4][2] = {};
  const int wr = wv >> 1, wc = wv & 1;
  const int rbase = lane & 15;
  const int kgrp = lane >> 4;

  for (int k0 = 0; k0 < DDIM; k0 += BK) {
    if (k0) __syncthreads();
    stage(k0);
    __syncthreads();
#pragma unroll
    for (int kk = 0; kk < 2; kk++) {
      bf16x8 af[4], gf[2], uf[2];
      int kbl = kk * 4 + kgrp;
#pragma unroll
      for (int i = 0; i < 4; i++) {
        int r = wr * 64 + i * 16 + rbase;
        af[i] = *(const bf16x8*)((const char*)&As[0] + r * 128 + ((kbl ^ (r & 7)) << 4));
      }
#pragma unroll
      for (int j = 0; j < 2; j++) {
        int r = wc * 32 + j * 16 + rbase;
        gf[j] = *(const bf16x8*)((const char*)&Bgs[0] + r * 128 + ((kbl ^ (r & 7)) << 4));
        uf[j] = *(const bf16x8*)((const char*)&Bus[0] + r * 128 + ((kbl ^ (r & 7)) << 4));
      }
#pragma unroll
      for (int i = 0; i < 4; i++)
#pragma unroll
        for (int j = 0; j < 2; j++) {
          accG[i][j] = __builtin_amdgcn_mfma_f32_16x16x32_bf16(af[i], gf[j], accG[i][j], 0, 0, 0);
          accU[i][j] = __builtin_amdgcn_mfma_f32_16x16x32_bf16(af[i], uf[j], accU[i][j], 0, 0, 0);
        }
    }
  }

  const int orow0 = tm + wr * 64 + (lane >> 4) * 4;
  const int ocol0 = tn + wc * 32 + (lane & 15);
#pragma unroll
  for (int i = 0; i < 4; i++)
#pragma unroll
    for (int j = 0; j < 2; j++)
#pragma unroll
      for (int r = 0; r < 4; r++) {
        int row = orow0 + i * 16 + r;
        if (row < validEnd) {
          float g = accG[i][j][r], u = accU[i][j][r];
          float h = g / (1.f + __expf(-g)) * u;
          Hout[(size_t)row * Nh + ocol0 + j * 16] = f2bf(h);
        }
      }
}

__global__ __launch_bounds__(256, 4) void k_down_all(
    const unsigned short* __restrict__ Hs,
    const unsigned short* __restrict__ Hr,
    const unsigned short* __restrict__ sWdT,
    const unsigned short* __restrict__ WdT,
    float* __restrict__ out,
    const int* __restrict__ offs, const int* __restrict__ cnt,
    const int* __restrict__ row_token, const float* __restrict__ row_w) {
  __shared__ unsigned short As[TM * BK];
  __shared__ unsigned short Bs[TND * BK];

  const int wg = xcd_swizzle();
  const int t = threadIdx.x;
  const int lane = t & 63, wv = t >> 6;
  const int lr  = lane >> 3;
  const int kbx = (lane & 7) ^ lr;

  int tm, tn, validEnd, K;
  bool routed;
  const unsigned short* pA[4];
  const unsigned short* pB[4];

  if (wg < SH_DN_WGS) {
    routed = false; K = SHDIM;
    tm = (wg / DN_NT) * TM;
    tn = (wg % DN_NT) * TND;
    validEnd = 0x7fffffff;
#pragma unroll
    for (int j = 0; j < 4; j++) {
      pA[j] = Hs + (size_t)(tm + (wv * 4 + j) * 8 + lr) * SHDIM;
      pB[j] = sWdT + (size_t)(tn + (wv * 4 + j) * 8 + lr) * SHDIM;
    }
  } else {
    routed = true; K = HDIM;
    int wgr = wg - SH_DN_WGS;
    tm = (wgr / DN_NT) * TM;
    tn = (wgr % DN_NT) * TND;
    if (tm >= offs[NEXP]) return;
    int e = 0;
#pragma unroll
    for (int i = 1; i < NEXP; i++) if (tm >= offs[i]) e = i;
    validEnd = offs[e] + cnt[e * CPAD];
    const unsigned short* B = WdT + (size_t)e * DDIM * HDIM;
#pragma unroll
    for (int j = 0; j < 4; j++) {
      pA[j] = Hr + (size_t)(tm + (wv * 4 + j) * 8 + lr) * HDIM;
      pB[j] = B + (size_t)(tn + (wv * 4 + j) * 8 + lr) * HDIM;
    }
  }

  auto stage = [&](int k0) {
#pragma unroll
    for (int j = 0; j < 4; j++) {
      gload16(pA[j] + k0 + kbx * 8, (void*)&As[(wv * 4 + j) * 512]);
      gload16(pB[j] + k0 + kbx * 8, (void*)&Bs[(wv * 4 + j) * 512]);
    }
  };

  f32x4 acc[4][4] = {};
  const int wr = wv >> 1, wc = wv & 1;
  const int rbase = lane & 15;
  const int kgrp = lane >> 4;

  for (int k0 = 0; k0 < K; k0 += BK) {
    if (k0) __syncthreads();
    stage(k0);
    __syncthreads();
#pragma unroll
    for (int kk = 0; kk < 2; kk++) {
      bf16x8 af[4], bf[4];
      int kbl = kk * 4 + kgrp;
#pragma unroll
      for (int i = 0; i < 4; i++) {
        int r = wr * 64 + i * 16 + rbase;
        af[i] = *(const bf16x8*)((const char*)&As[0] + r * 128 + ((kbl ^ (r & 7)) << 4));
      }
#pragma unroll
      for (int j = 0; j < 4; j++) {
        int r = wc * 64 + j * 16 + rbase;
        bf[j] = *(const bf16x8*)((const char*)&Bs[0] + r * 128 + ((kbl ^ (r & 7)) << 4));
      }
#pragma unroll
      for (int i = 0; i < 4; i++)
#pragma unroll
        for (int j = 0; j < 4; j++)
          acc[i][j] = __builtin_amdgcn_mfma_f32_16x16x32_bf16(af[i], bf[j], acc[i][j], 0, 0, 0);
    }
  }

  const int orow0 = tm + wr * 64 + (lane >> 4) * 4;
  const int ocol0 = tn + wc * 64 + (lane & 15);
#pragma unroll
  for (int i = 0; i < 4; i++)
#pragma unroll
    for (int j = 0; j < 4; j++)
#pragma unroll
      for (int r = 0; r < 4; r++) {
        int row = orow0 + i * 16 + r;
        int col = ocol0 + j * 16;
        if (row < validEnd) {
          int tok; float wgt;
          if (routed) { tok = row_token[row]; wgt = row_w[row]; }
          else        { tok = row;            wgt = 1.f; }
          atomicAdd(&out[(size_t)tok * DDIM + col], acc[i][j][r] * wgt);
        }
      }
}

__global__ void k_tail(const float* __restrict__ probsum, const int* __restrict__ cnt,
                       float* __restrict__ out_tail) {
  if (threadIdx.x == 0) {
    float bal = 0.f;
    for (int e = 0; e < NEXP; e++) {
      float frac = (float)cnt[e * CPAD] / (float)(N_TOK * 2);
      bal += frac * (probsum[e * CPAD] / (float)N_TOK);
    }
    out_tail[0] = 0.01f * (float)NEXP * bal;
  }
  if (threadIdx.x < NEXP) out_tail[1 + threadIdx.x] = (float)cnt[threadIdx.x * CPAD];
}

// ---------------- launch ----------------

extern "C" void kernel_launch(void* const* d_in, const int* in_sizes, int n_in,
                              void* d_out, int out_size, void* d_ws, size_t ws_size,
                              hipStream_t stream) {
  const float* x   = (const float*)d_in[0];
  const float* rw  = (const float*)d_in[1];
  const float* rb  = (const float*)d_in[2];
  const float* Wg  = (const float*)d_in[3];
  const float* Wu  = (const float*)d_in[4];
  const float* Wd  = (const float*)d_in[5];
  const float* sWg = (const float*)d_in[6];
  const float* sWu = (const float*)d_in[7];
  const float* sWd = (const float*)d_in[8];
  float* out = (float*)d_out;

  uint8_t* w = (uint8_t*)d_ws;
  size_t off = 0;
  auto alloc = [&](size_t bytes) -> void* {
    void* p = w + off;
    off += (bytes + 255) & ~(size_t)255;
    return p;
  };

  int*   cnt     = (int*)alloc(NEXP * CPAD * 4);
  int*   cursor  = (int*)alloc(NEXP * CPAD * 4);
  float* probsum = (float*)alloc(NEXP * CPAD * 4);
  int*   offs    = (int*)alloc((NEXP + 1) * 4);
  int*   tok_idx = (int*)alloc((size_t)N_TOK * 2 * 4);
  float* tok_w   = (float*)alloc((size_t)N_TOK * 2 * 4);
  int*   row_tok = (int*)alloc((size_t)MT_R * TM * 4);
  float* row_w   = (float*)alloc((size_t)MT_R * TM * 4);
  float* probs   = (float*)alloc((size_t)N_TOK * NEXP * 4);
  unsigned short* Xbf  = (unsigned short*)alloc((size_t)N_TOK * DDIM * 2);
  unsigned short* Hs   = (unsigned short*)alloc((size_t)N_TOK * SHDIM * 2);
  unsigned short* Hr   = (unsigned short*)alloc((size_t)MT_R * TM * HDIM * 2);
  unsigned short* WgT  = (unsigned short*)alloc((size_t)NEXP * HDIM * DDIM * 2);
  unsigned short* WuT  = (unsigned short*)alloc((size_t)NEXP * HDIM * DDIM * 2);
  unsigned short* WdT  = (unsigned short*)alloc((size_t)NEXP * DDIM * HDIM * 2);
  unsigned short* sWgT = (unsigned short*)alloc((size_t)SHDIM * DDIM * 2);
  unsigned short* sWuT = (unsigned short*)alloc((size_t)SHDIM * DDIM * 2);
  unsigned short* sWdT = (unsigned short*)alloc((size_t)DDIM * SHDIM * 2);

  if (off > ws_size) return;

  k_zero<<<1, 256, 0, stream>>>(cnt, cursor, probsum);
  k_router<<<N_TOK / 16, 256, 0, stream>>>(x, rw, rb, cnt, tok_idx, tok_w, probs);
  k_psum<<<64, 256, 0, stream>>>(probs, probsum);
  k_prefix<<<1, 1, 0, stream>>>(cnt, offs);
  k_assign<<<(N_TOK * 2) / 256, 256, 0, stream>>>(tok_idx, tok_w, cursor, offs, row_tok, row_w);
  k_f32_to_bf16<<<(N_TOK * DDIM / 4 + 255) / 256, 256, 0, stream>>>(x, Xbf, N_TOK * DDIM / 4);

  k_transpose2<<<dim3(HDIM / 64, DDIM / 64, NEXP), 256, 0, stream>>>(Wg, WgT, DDIM, HDIM);
  k_transpose2<<<dim3(HDIM / 64, DDIM / 64, NEXP), 256, 0, stream>>>(Wu, WuT, DDIM, HDIM);
  k_transpose2<<<dim3(DDIM / 64, HDIM / 64, NEXP), 256, 0, stream>>>(Wd, WdT, HDIM, DDIM);
  k_transpose2<<<dim3(SHDIM / 64, DDIM / 64, 1), 256, 0, stream>>>(sWg, sWgT, DDIM, SHDIM);
  k_transpose2<<<dim3(SHDIM / 64, DDIM / 64, 1), 256, 0, stream>>>(sWu, sWuT, DDIM, SHDIM);
  k_transpose2<<<dim3(DDIM / 64, SHDIM / 64, 1), 256, 0, stream>>>(sWd, sWdT, SHDIM, DDIM);

  // zero the main output region (both down segments accumulate atomically)
  hipMemsetAsync(out, 0, (size_t)N_TOK * DDIM * 4, stream);

  k_gateup_all<<<GU_WGS, 256, 0, stream>>>(
      Xbf, sWgT, sWuT, WgT, WuT, Hs, Hr, offs, cnt, row_tok);
  k_down_all<<<DN_WGS, 256, 0, stream>>>(
      Hs, Hr, sWdT, WdT, out, offs, cnt, row_tok, row_w);

  k_tail<<<1, 32, 0, stream>>>(probsum, cnt, out + (size_t)N_TOK * DDIM);
}

// Round 5
// 426.479 us; speedup vs baseline: 1.8383x; 1.1083x over previous
//
#include <hip/hip_runtime.h>
#include <stdint.h>

#define N_TOK 8192
#define DDIM  1024
#define NEXP  16
#define HDIM  1024
#define SHDIM 2048
#define TM 128
#define BK 64
#define MT_R 144       // max routed m-tiles: 16384 + 15*127 padded -> <= 18432 rows

// merged grid geometry
#define SH_GU_NT  (SHDIM / 64)                 // 32
#define SH_GU_WGS ((N_TOK / TM) * SH_GU_NT)    // 2048
#define RT_GU_NT  (HDIM / 64)                  // 16
#define RT_GU_WGS (MT_R * RT_GU_NT)            // 2304
#define GU_WGS    (SH_GU_WGS + RT_GU_WGS)      // 4352  (%8==0)

#define TND 128
#define DN_NT     (DDIM / TND)                 // 8
#define SH_DN_WGS ((N_TOK / TM) * DN_NT)       // 512
#define RT_DN_WGS (MT_R * DN_NT)               // 1152
#define DN_WGS    (SH_DN_WGS + RT_DN_WGS)      // 1664  (%8==0)

#define CPAD 16   // counter padding: one 64B line per counter

typedef __bf16 bf16x8 __attribute__((ext_vector_type(8)));
typedef float  f32x4  __attribute__((ext_vector_type(4)));

__device__ __forceinline__ unsigned short f2bf(float f) {
  union { float f; unsigned u; } v; v.f = f;
  unsigned r = v.u + 0x7fffu + ((v.u >> 16) & 1u);
  return (unsigned short)(r >> 16);
}
__device__ __forceinline__ float bf2f(unsigned short u) {
  union { unsigned u; float f; } v; v.u = (unsigned)u << 16; return v.f;
}

__device__ __forceinline__ void gload16(const void* g, void* l) {
  __builtin_amdgcn_global_load_lds(
      (const __attribute__((address_space(1))) void*)g,
      (__attribute__((address_space(3))) void*)l, 16, 0, 0);
}

// XCD-aware bijective block swizzle (requires gridDim.x % 8 == 0).
__device__ __forceinline__ int xcd_swizzle() {
  int nwg = (int)gridDim.x;
  int b = (int)blockIdx.x;
  return (b & 7) * (nwg >> 3) + (b >> 3);
}

// ---------------- small setup kernels ----------------

__global__ void k_zero(int* cnt, int* cursor, float* probsum) {
  int t = threadIdx.x;
  if (t < NEXP * CPAD) { cnt[t] = 0; cursor[t] = 0; probsum[t] = 0.f; }
}

// 512 blocks x 256 threads; 16 tokens/block (4 per wave). Also emits Xbf.
__global__ __launch_bounds__(256) void k_router(
    const float* __restrict__ x, const float* __restrict__ rw,
    const float* __restrict__ rb, int* __restrict__ cnt,
    int* __restrict__ tok_idx, float* __restrict__ tok_w,
    float* __restrict__ probs, unsigned short* __restrict__ Xbf) {
  __shared__ float rwT[NEXP * 1024];
  const int t = threadIdx.x;
  {
    int dbase = t >> 2, e0 = (t & 3) * 4;
#pragma unroll
    for (int c = 0; c < 16; c++) {
      int d = dbase + 64 * c;
      float4 v = *(const float4*)(rw + (size_t)d * NEXP + e0);
      rwT[(e0 + 0) * 1024 + d] = v.x;
      rwT[(e0 + 1) * 1024 + d] = v.y;
      rwT[(e0 + 2) * 1024 + d] = v.z;
      rwT[(e0 + 3) * 1024 + d] = v.w;
    }
  }
  __syncthreads();
  const int lane = t & 63, wv = t >> 6;
  const int tok0 = blockIdx.x * 16 + wv * 4;
  float acc[4][NEXP];
#pragma unroll
  for (int tt = 0; tt < 4; tt++)
#pragma unroll
    for (int e = 0; e < NEXP; e++) acc[tt][e] = 0.f;

#pragma unroll
  for (int c = 0; c < 4; c++) {
    int d = lane * 4 + 256 * c;
    float4 xv[4];
#pragma unroll
    for (int tt = 0; tt < 4; tt++) {
      xv[tt] = *(const float4*)(x + (size_t)(tok0 + tt) * DDIM + d);
      ushort4 o;
      o.x = f2bf(xv[tt].x); o.y = f2bf(xv[tt].y);
      o.z = f2bf(xv[tt].z); o.w = f2bf(xv[tt].w);
      *(ushort4*)(Xbf + (size_t)(tok0 + tt) * DDIM + d) = o;
    }
#pragma unroll
    for (int e = 0; e < NEXP; e++) {
      float4 w4 = *(const float4*)(&rwT[e * 1024 + d]);
#pragma unroll
      for (int tt = 0; tt < 4; tt++) {
        acc[tt][e] = fmaf(xv[tt].x, w4.x, acc[tt][e]);
        acc[tt][e] = fmaf(xv[tt].y, w4.y, acc[tt][e]);
        acc[tt][e] = fmaf(xv[tt].z, w4.z, acc[tt][e]);
        acc[tt][e] = fmaf(xv[tt].w, w4.w, acc[tt][e]);
      }
    }
  }
#pragma unroll
  for (int tt = 0; tt < 4; tt++)
#pragma unroll
    for (int e = 0; e < NEXP; e++) {
      float v = acc[tt][e];
#pragma unroll
      for (int o = 32; o; o >>= 1) v += __shfl_xor(v, o);
      acc[tt][e] = v;
    }

#pragma unroll
  for (int tt = 0; tt < 4; tt++) {
    if (lane == tt) {
      int tok = tok0 + tt;
      float mx = acc[tt][0];
#pragma unroll
      for (int e = 1; e < NEXP; e++) mx = fmaxf(mx, acc[tt][e]);
      float p[NEXP]; float s = 0.f;
#pragma unroll
      for (int e = 0; e < NEXP; e++) { p[e] = __expf(acc[tt][e] - mx); s += p[e]; }
      float inv = 1.f / s;
      float* pdst = probs + (size_t)tok * NEXP;
#pragma unroll
      for (int e = 0; e < NEXP; e++) { p[e] *= inv; pdst[e] = p[e]; }
      int i0 = 0; float b0 = acc[tt][0] + rb[0];
#pragma unroll
      for (int e = 1; e < NEXP; e++) { float v = acc[tt][e] + rb[e]; if (v > b0) { b0 = v; i0 = e; } }
      int i1 = -1; float b1 = -3.4e38f;
#pragma unroll
      for (int e = 0; e < NEXP; e++) {
        if (e == i0) continue;
        float v = acc[tt][e] + rb[e]; if (v > b1) { b1 = v; i1 = e; }
      }
      float w0 = 0.f, w1 = 0.f;
#pragma unroll
      for (int e = 0; e < NEXP; e++) { if (e == i0) w0 = p[e]; if (e == i1) w1 = p[e]; }
      float ssum = fmaxf(w0 + w1, 1e-9f);
      w0 /= ssum; w1 /= ssum;
      atomicAdd(&cnt[i0 * CPAD], 1); atomicAdd(&cnt[i1 * CPAD], 1);
      tok_idx[tok * 2]     = i0; tok_idx[tok * 2 + 1] = i1;
      tok_w[tok * 2]       = w0; tok_w[tok * 2 + 1]   = w1;
    }
  }
}

__global__ __launch_bounds__(256) void k_psum(
    const float* __restrict__ probs, float* __restrict__ probsum) {
  __shared__ float ps[NEXP];
  const int t = threadIdx.x;
  if (t < NEXP) ps[t] = 0.f;
  __syncthreads();
  int e = t & 15, trow = t >> 4;
  float s = 0.f;
#pragma unroll
  for (int c = 0; c < 8; c++) {
    int tok = blockIdx.x * 128 + c * 16 + trow;
    s += probs[(size_t)tok * NEXP + e];
  }
  atomicAdd(&ps[e], s);
  __syncthreads();
  if (t < NEXP) atomicAdd(&probsum[t * CPAD], ps[t]);
}

__global__ void k_prefix(const int* __restrict__ cnt, int* __restrict__ offs) {
  if (threadIdx.x == 0) {
    int o = 0;
    for (int e = 0; e < NEXP; e++) { offs[e] = o; o += ((cnt[e * CPAD] + 127) & ~127); }
    offs[NEXP] = o;
  }
}

// one thread per (token, k) slot: assign routed row, record both directions
__global__ __launch_bounds__(256) void k_assign(
    const int* __restrict__ tok_idx, const float* __restrict__ tok_w,
    int* __restrict__ cursor, const int* __restrict__ offs,
    int* __restrict__ row_token, int* __restrict__ tok_rows) {
  int i = blockIdx.x * 256 + threadIdx.x;
  if (i >= N_TOK * 2) return;
  int e = tok_idx[i];
  int pos = atomicAdd(&cursor[e * CPAD], 1);
  int row = offs[e] + pos;
  row_token[row] = i >> 1;
  tok_rows[i] = row;
}

// ---------------- transposes (fp32 [R][C] -> bf16 [C][R]) ----------------

__device__ __forceinline__ void do_transpose64(
    const float* __restrict__ src, unsigned short* __restrict__ dst,
    int R, int C, int tc, int tr, float* tile /* 64*65 */) {
  int rx = threadIdx.x >> 4;
  int cx = (threadIdx.x & 15) * 4;
#pragma unroll
  for (int p = 0; p < 4; p++) {
    int r = p * 16 + rx;
    float4 v = *(const float4*)(src + (size_t)(tr + r) * C + tc + cx);
    tile[(cx + 0) * 65 + r] = v.x;
    tile[(cx + 1) * 65 + r] = v.y;
    tile[(cx + 2) * 65 + r] = v.z;
    tile[(cx + 3) * 65 + r] = v.w;
  }
  __syncthreads();
#pragma unroll
  for (int p = 0; p < 4; p++) {
    int c = p * 16 + rx;
    float v0 = tile[c * 65 + cx + 0];
    float v1 = tile[c * 65 + cx + 1];
    float v2 = tile[c * 65 + cx + 2];
    float v3 = tile[c * 65 + cx + 3];
    ushort4 o; o.x = f2bf(v0); o.y = f2bf(v1); o.z = f2bf(v2); o.w = f2bf(v3);
    *(ushort4*)(dst + (size_t)(tc + c) * R + tr + cx) = o;
  }
}

// 12288 blocks: Wg/Wu/Wd, each 16 matrices of 1024x1024 (256 tiles each)
__global__ __launch_bounds__(256) void k_transpose_big(
    const float* __restrict__ Wg, const float* __restrict__ Wu,
    const float* __restrict__ Wd, unsigned short* __restrict__ WgT,
    unsigned short* __restrict__ WuT, unsigned short* __restrict__ WdT) {
  __shared__ float tile[64 * 65];
  int id = blockIdx.x;
  int which = id >> 12;          // /4096
  int rem = id & 4095;
  int mat = rem >> 8;
  int tl  = rem & 255;
  int bx = tl & 15, by = tl >> 4;
  const float* src = (which == 0 ? Wg : which == 1 ? Wu : Wd) + (size_t)mat * 1024 * 1024;
  unsigned short* dst = (which == 0 ? WgT : which == 1 ? WuT : WdT) + (size_t)mat * 1024 * 1024;
  do_transpose64(src, dst, 1024, 1024, bx * 64, by * 64, tile);
}

// 1536 blocks: sWg, sWu (1024x2048, 512 tiles each), sWd (2048x1024, 512)
__global__ __launch_bounds__(256) void k_transpose_sh(
    const float* __restrict__ sWg, const float* __restrict__ sWu,
    const float* __restrict__ sWd, unsigned short* __restrict__ sWgT,
    unsigned short* __restrict__ sWuT, unsigned short* __restrict__ sWdT) {
  __shared__ float tile[64 * 65];
  int id = blockIdx.x;
  if (id < 1024) {
    const float* src = id < 512 ? sWg : sWu;
    unsigned short* dst = id < 512 ? sWgT : sWuT;
    int tl = id & 511;
    int bx = tl & 31, by = tl >> 5;
    do_transpose64(src, dst, 1024, 2048, bx * 64, by * 64, tile);
  } else {
    int tl = id - 1024;
    int bx = tl & 15, by = tl >> 4;
    do_transpose64(sWd, sWdT, 2048, 1024, bx * 64, by * 64, tile);
  }
}

// ---------------- merged GEMM kernels (m97 structure) ----------------
// Single-buffered 32KB LDS, 2-barrier K-loop, global_load_lds width 16,
// 16B-unit XOR swizzle, XCD-aware block swizzle, banded tile order
// (bands of 8 n-tiles, m sweeps fastest inside a band -> L2 window fits).

__global__ __launch_bounds__(256, 4) void k_gateup_all(
    const unsigned short* __restrict__ Xbf,
    const unsigned short* __restrict__ sWgT,
    const unsigned short* __restrict__ sWuT,
    const unsigned short* __restrict__ WgT,
    const unsigned short* __restrict__ WuT,
    unsigned short* __restrict__ Hs,
    unsigned short* __restrict__ Hr,
    const int* __restrict__ offs, const int* __restrict__ cnt,
    const int* __restrict__ row_token) {
  __shared__ unsigned short As[TM * BK];
  __shared__ unsigned short Bgs[64 * BK];
  __shared__ unsigned short Bus[64 * BK];

  const int wg = xcd_swizzle();
  const int t = threadIdx.x;
  const int lane = t & 63, wv = t >> 6;
  const int lr  = lane >> 3;            // row within 8-row chunk
  const int kbx = (lane & 7) ^ lr;      // pre-swizzled 16B-unit column

  int tm, tn, validEnd, Nh;
  const unsigned short *Bgp, *Bup;
  unsigned short* Hout;
  const unsigned short* pA[4];

  if (wg < SH_GU_WGS) {
    // banded decode: band of 8 nt, mt fastest-ish (mt = r>>3)
    int band = wg >> 9;          // / (64mt * 8nt)
    int r = wg & 511;
    tm = (r >> 3) * TM;
    tn = (band * 8 + (r & 7)) * 64;
    validEnd = 0x7fffffff;
    Bgp = sWgT; Bup = sWuT;
    Hout = Hs; Nh = SHDIM;
#pragma unroll
    for (int j = 0; j < 4; j++)
      pA[j] = Xbf + (size_t)(tm + (wv * 4 + j) * 8 + lr) * DDIM;
  } else {
    int u = wg - SH_GU_WGS;
    int band = u / 1152;         // / (144mt * 8nt)
    int r = u % 1152;
    tm = (r >> 3) * TM;
    tn = (band * 8 + (r & 7)) * 64;
    if (tm >= offs[NEXP]) return;
    int e = 0;
#pragma unroll
    for (int i = 1; i < NEXP; i++) if (tm >= offs[i]) e = i;
    validEnd = offs[e] + cnt[e * CPAD];
    Bgp = WgT + (size_t)e * HDIM * DDIM;
    Bup = WuT + (size_t)e * HDIM * DDIM;
    Hout = Hr; Nh = HDIM;
#pragma unroll
    for (int j = 0; j < 4; j++) {
      int row = tm + (wv * 4 + j) * 8 + lr;
      int tok = row < validEnd ? row_token[row] : 0;
      pA[j] = Xbf + (size_t)tok * DDIM;
    }
  }
  const unsigned short* pBg[2];
  const unsigned short* pBu[2];
#pragma unroll
  for (int j = 0; j < 2; j++) {
    int row = tn + (wv * 2 + j) * 8 + lr;
    pBg[j] = Bgp + (size_t)row * DDIM;
    pBu[j] = Bup + (size_t)row * DDIM;
  }

  auto stage = [&](int k0) {
#pragma unroll
    for (int j = 0; j < 4; j++)
      gload16(pA[j] + k0 + kbx * 8, (void*)&As[(wv * 4 + j) * 512]);
#pragma unroll
    for (int j = 0; j < 2; j++) {
      gload16(pBg[j] + k0 + kbx * 8, (void*)&Bgs[(wv * 2 + j) * 512]);
      gload16(pBu[j] + k0 + kbx * 8, (void*)&Bus[(wv * 2 + j) * 512]);
    }
  };

  f32x4 accG[4][2] = {};
  f32x4 accU[4][2] = {};
  const int wr = wv >> 1, wc = wv & 1;
  const int rbase = lane & 15;
  const int kgrp = lane >> 4;

  for (int k0 = 0; k0 < DDIM; k0 += BK) {
    if (k0) __syncthreads();
    stage(k0);
    __syncthreads();
#pragma unroll
    for (int kk = 0; kk < 2; kk++) {
      bf16x8 af[4], gf[2], uf[2];
      int kbl = kk * 4 + kgrp;
#pragma unroll
      for (int i = 0; i < 4; i++) {
        int r = wr * 64 + i * 16 + rbase;
        af[i] = *(const bf16x8*)((const char*)&As[0] + r * 128 + ((kbl ^ (r & 7)) << 4));
      }
#pragma unroll
      for (int j = 0; j < 2; j++) {
        int r = wc * 32 + j * 16 + rbase;
        gf[j] = *(const bf16x8*)((const char*)&Bgs[0] + r * 128 + ((kbl ^ (r & 7)) << 4));
        uf[j] = *(const bf16x8*)((const char*)&Bus[0] + r * 128 + ((kbl ^ (r & 7)) << 4));
      }
#pragma unroll
      for (int i = 0; i < 4; i++)
#pragma unroll
        for (int j = 0; j < 2; j++) {
          accG[i][j] = __builtin_amdgcn_mfma_f32_16x16x32_bf16(af[i], gf[j], accG[i][j], 0, 0, 0);
          accU[i][j] = __builtin_amdgcn_mfma_f32_16x16x32_bf16(af[i], uf[j], accU[i][j], 0, 0, 0);
        }
    }
  }

  const int orow0 = tm + wr * 64 + (lane >> 4) * 4;
  const int ocol0 = tn + wc * 32 + (lane & 15);
#pragma unroll
  for (int i = 0; i < 4; i++)
#pragma unroll
    for (int j = 0; j < 2; j++)
#pragma unroll
      for (int r = 0; r < 4; r++) {
        int row = orow0 + i * 16 + r;
        if (row < validEnd) {
          float g = accG[i][j][r], u = accU[i][j][r];
          float h = g / (1.f + __expf(-g)) * u;
          Hout[(size_t)row * Nh + ocol0 + j * 16] = f2bf(h);
        }
      }
}

__global__ __launch_bounds__(256, 4) void k_down_all(
    const unsigned short* __restrict__ Hs,
    const unsigned short* __restrict__ Hr,
    const unsigned short* __restrict__ sWdT,
    const unsigned short* __restrict__ WdT,
    float* __restrict__ out,
    unsigned short* __restrict__ Rbuf,
    const int* __restrict__ offs, const int* __restrict__ cnt) {
  __shared__ unsigned short As[TM * BK];
  __shared__ unsigned short Bs[TND * BK];

  const int wg = xcd_swizzle();
  const int t = threadIdx.x;
  const int lane = t & 63, wv = t >> 6;
  const int lr  = lane >> 3;
  const int kbx = (lane & 7) ^ lr;

  int tm, tn, validEnd, K;
  bool routed;
  const unsigned short* pA[4];
  const unsigned short* pB[4];

  if (wg < SH_DN_WGS) {
    routed = false; K = SHDIM;
    tm = (wg >> 3) * TM;
    tn = (wg & 7) * TND;
    validEnd = 0x7fffffff;
#pragma unroll
    for (int j = 0; j < 4; j++) {
      pA[j] = Hs + (size_t)(tm + (wv * 4 + j) * 8 + lr) * SHDIM;
      pB[j] = sWdT + (size_t)(tn + (wv * 4 + j) * 8 + lr) * SHDIM;
    }
  } else {
    routed = true; K = HDIM;
    int wgr = wg - SH_DN_WGS;
    tm = (wgr >> 3) * TM;
    tn = (wgr & 7) * TND;
    if (tm >= offs[NEXP]) return;
    int e = 0;
#pragma unroll
    for (int i = 1; i < NEXP; i++) if (tm >= offs[i]) e = i;
    validEnd = offs[e] + cnt[e * CPAD];
    const unsigned short* B = WdT + (size_t)e * DDIM * HDIM;
#pragma unroll
    for (int j = 0; j < 4; j++) {
      pA[j] = Hr + (size_t)(tm + (wv * 4 + j) * 8 + lr) * HDIM;
      pB[j] = B + (size_t)(tn + (wv * 4 + j) * 8 + lr) * HDIM;
    }
  }

  auto stage = [&](int k0) {
#pragma unroll
    for (int j = 0; j < 4; j++) {
      gload16(pA[j] + k0 + kbx * 8, (void*)&As[(wv * 4 + j) * 512]);
      gload16(pB[j] + k0 + kbx * 8, (void*)&Bs[(wv * 4 + j) * 512]);
    }
  };

  f32x4 acc[4][4] = {};
  const int wr = wv >> 1, wc = wv & 1;
  const int rbase = lane & 15;
  const int kgrp = lane >> 4;

  for (int k0 = 0; k0 < K; k0 += BK) {
    if (k0) __syncthreads();
    stage(k0);
    __syncthreads();
#pragma unroll
    for (int kk = 0; kk < 2; kk++) {
      bf16x8 af[4], bf[4];
      int kbl = kk * 4 + kgrp;
#pragma unroll
      for (int i = 0; i < 4; i++) {
        int r = wr * 64 + i * 16 + rbase;
        af[i] = *(const bf16x8*)((const char*)&As[0] + r * 128 + ((kbl ^ (r & 7)) << 4));
      }
#pragma unroll
      for (int j = 0; j < 4; j++) {
        int r = wc * 64 + j * 16 + rbase;
        bf[j] = *(const bf16x8*)((const char*)&Bs[0] + r * 128 + ((kbl ^ (r & 7)) << 4));
      }
#pragma unroll
      for (int i = 0; i < 4; i++)
#pragma unroll
        for (int j = 0; j < 4; j++)
          acc[i][j] = __builtin_amdgcn_mfma_f32_16x16x32_bf16(af[i], bf[j], acc[i][j], 0, 0, 0);
    }
  }

  const int orow0 = tm + wr * 64 + (lane >> 4) * 4;
  const int ocol0 = tn + wc * 64 + (lane & 15);
#pragma unroll
  for (int i = 0; i < 4; i++)
#pragma unroll
    for (int j = 0; j < 4; j++)
#pragma unroll
      for (int r = 0; r < 4; r++) {
        int row = orow0 + i * 16 + r;
        int col = ocol0 + j * 16;
        if (routed) {
          if (row < validEnd) Rbuf[(size_t)row * DDIM + col] = f2bf(acc[i][j][r]);
        } else {
          out[(size_t)row * DDIM + col] = acc[i][j][r];
        }
      }
}

// out[tok] += w0 * Rbuf[r0] + w1 * Rbuf[r1]
__global__ __launch_bounds__(256) void k_combine(
    float* __restrict__ out, const unsigned short* __restrict__ Rbuf,
    const int* __restrict__ tok_rows, const float* __restrict__ tok_w) {
  int tok = blockIdx.x;
  int c = threadIdx.x;
  int r0 = tok_rows[tok * 2], r1 = tok_rows[tok * 2 + 1];
  float w0 = tok_w[tok * 2],  w1 = tok_w[tok * 2 + 1];
  float4 o  = ((const float4*)(out + (size_t)tok * DDIM))[c];
  ushort4 a = ((const ushort4*)(Rbuf + (size_t)r0 * DDIM))[c];
  ushort4 b = ((const ushort4*)(Rbuf + (size_t)r1 * DDIM))[c];
  o.x += w0 * bf2f(a.x) + w1 * bf2f(b.x);
  o.y += w0 * bf2f(a.y) + w1 * bf2f(b.y);
  o.z += w0 * bf2f(a.z) + w1 * bf2f(b.z);
  o.w += w0 * bf2f(a.w) + w1 * bf2f(b.w);
  ((float4*)(out + (size_t)tok * DDIM))[c] = o;
}

__global__ void k_tail(const float* __restrict__ probsum, const int* __restrict__ cnt,
                       float* __restrict__ out_tail) {
  if (threadIdx.x == 0) {
    float bal = 0.f;
    for (int e = 0; e < NEXP; e++) {
      float frac = (float)cnt[e * CPAD] / (float)(N_TOK * 2);
      bal += frac * (probsum[e * CPAD] / (float)N_TOK);
    }
    out_tail[0] = 0.01f * (float)NEXP * bal;
  }
  if (threadIdx.x < NEXP) out_tail[1 + threadIdx.x] = (float)cnt[threadIdx.x * CPAD];
}

// ---------------- launch ----------------

extern "C" void kernel_launch(void* const* d_in, const int* in_sizes, int n_in,
                              void* d_out, int out_size, void* d_ws, size_t ws_size,
                              hipStream_t stream) {
  const float* x   = (const float*)d_in[0];
  const float* rw  = (const float*)d_in[1];
  const float* rb  = (const float*)d_in[2];
  const float* Wg  = (const float*)d_in[3];
  const float* Wu  = (const float*)d_in[4];
  const float* Wd  = (const float*)d_in[5];
  const float* sWg = (const float*)d_in[6];
  const float* sWu = (const float*)d_in[7];
  const float* sWd = (const float*)d_in[8];
  float* out = (float*)d_out;

  uint8_t* w = (uint8_t*)d_ws;
  size_t off = 0;
  auto alloc = [&](size_t bytes) -> void* {
    void* p = w + off;
    off += (bytes + 255) & ~(size_t)255;
    return p;
  };

  int*   cnt      = (int*)alloc(NEXP * CPAD * 4);
  int*   cursor   = (int*)alloc(NEXP * CPAD * 4);
  float* probsum  = (float*)alloc(NEXP * CPAD * 4);
  int*   offs     = (int*)alloc((NEXP + 1) * 4);
  int*   tok_idx  = (int*)alloc((size_t)N_TOK * 2 * 4);
  float* tok_w    = (float*)alloc((size_t)N_TOK * 2 * 4);
  int*   tok_rows = (int*)alloc((size_t)N_TOK * 2 * 4);
  int*   row_tok  = (int*)alloc((size_t)MT_R * TM * 4);
  float* probs    = (float*)alloc((size_t)N_TOK * NEXP * 4);
  unsigned short* Xbf  = (unsigned short*)alloc((size_t)N_TOK * DDIM * 2);
  unsigned short* Hs   = (unsigned short*)alloc((size_t)N_TOK * SHDIM * 2);
  unsigned short* Hr   = (unsigned short*)alloc((size_t)MT_R * TM * HDIM * 2);
  unsigned short* Rbuf = (unsigned short*)alloc((size_t)MT_R * TM * DDIM * 2);
  unsigned short* WgT  = (unsigned short*)alloc((size_t)NEXP * HDIM * DDIM * 2);
  unsigned short* WuT  = (unsigned short*)alloc((size_t)NEXP * HDIM * DDIM * 2);
  unsigned short* WdT  = (unsigned short*)alloc((size_t)NEXP * DDIM * HDIM * 2);
  unsigned short* sWgT = (unsigned short*)alloc((size_t)SHDIM * DDIM * 2);
  unsigned short* sWuT = (unsigned short*)alloc((size_t)SHDIM * DDIM * 2);
  unsigned short* sWdT = (unsigned short*)alloc((size_t)DDIM * SHDIM * 2);

  if (off > ws_size) return;

  k_zero<<<1, 256, 0, stream>>>(cnt, cursor, probsum);
  k_router<<<N_TOK / 16, 256, 0, stream>>>(x, rw, rb, cnt, tok_idx, tok_w, probs, Xbf);
  k_psum<<<64, 256, 0, stream>>>(probs, probsum);
  k_prefix<<<1, 1, 0, stream>>>(cnt, offs);
  k_assign<<<(N_TOK * 2) / 256, 256, 0, stream>>>(tok_idx, tok_w, cursor, offs, row_tok, tok_rows);

  k_transpose_big<<<12288, 256, 0, stream>>>(Wg, Wu, Wd, WgT, WuT, WdT);
  k_transpose_sh<<<1536, 256, 0, stream>>>(sWg, sWu, sWd, sWgT, sWuT, sWdT);

  k_gateup_all<<<GU_WGS, 256, 0, stream>>>(
      Xbf, sWgT, sWuT, WgT, WuT, Hs, Hr, offs, cnt, row_tok);
  k_down_all<<<DN_WGS, 256, 0, stream>>>(
      Hs, Hr, sWdT, WdT, out, Rbuf, offs, cnt);
  k_combine<<<N_TOK, 256, 0, stream>>>(out, Rbuf, tok_rows, tok_w);

  k_tail<<<1, 32, 0, stream>>>(probsum, cnt, out + (size_t)N_TOK * DDIM);
}